// Round 4
// baseline (440.080 us; speedup 1.0000x reference)
//
#include <hip/hip_runtime.h>

typedef __bf16 bf16;
typedef __bf16 bf16x8 __attribute__((ext_vector_type(8)));
typedef float f32x4 __attribute__((ext_vector_type(4)));
typedef short s16x4 __attribute__((ext_vector_type(4)));

#define B_ 2
#define S_ 2048
#define D_ 2048
#define H_ 16
#define HKV_ 4
#define HD_ 128
#define QKVW 3072
#define QKW 2560                    // q+k columns (V handled separately)
#define SCALE 0.08838834764831845f  // 1/sqrt(128)
#define NEGINF -30000.0f            // finite -inf: exp underflows to 0, no inf-inf

// async global->LDS DMA, 16B per lane; LDS dest = wave-uniform base + lane*16
__device__ inline void gload16(const void* g, void* l) {
  __builtin_amdgcn_global_load_lds((const __attribute__((address_space(1))) unsigned int*)g,
                                   (__attribute__((address_space(3))) unsigned int*)l, 16, 0, 0);
}

__device__ inline unsigned short bfb(float v) {
  union { bf16 h; unsigned short u; } c;
  c.h = (bf16)v;
  return c.u;
}

// ---------------- dtype detection: bf16 or fp32 inputs? ----------------
__global__ void detect_dtype(const unsigned* __restrict__ xw, int* __restrict__ flag) {
  __shared__ int cnt;
  if (threadIdx.x == 0) cnt = 0;
  __syncthreads();
  unsigned w = xw[(size_t)threadIdx.x * 16384];
  unsigned low = w & 0xFFFFu;
  int e = (int)((low >> 7) & 0xFF);
  int vote = (low == 0u || (e >= 100 && e <= 140)) ? 1 : 0;
  atomicAdd(&cnt, vote);
  __syncthreads();
  if (threadIdx.x == 0) *flag = (cnt >= 128) ? 1 : 0;  // 1 = bf16, 0 = fp32
}

// ---------------- fused Wq/Wk/Wv transpose -> wqkvT (B^T layout) ----------------
__global__ __launch_bounds__(256) void transpose_qkvw(
    const void* __restrict__ Wq, const void* __restrict__ Wk, const void* __restrict__ Wv,
    bf16* __restrict__ wqkvT, const int* __restrict__ flag) {
  int z = blockIdx.z;
  const void* in = (z == 0) ? Wq : (z == 1) ? Wk : Wv;
  int cols = (z == 0) ? 2048 : 512;
  bf16* out = wqkvT + ((z == 0) ? 0 : (z == 1) ? 2048 * 2048 : 2560 * 2048);
  if (blockIdx.x * 32 >= cols) return;
  int fm = *flag;
  __shared__ float tile[32][33];
  int c0 = blockIdx.x * 32, r0 = blockIdx.y * 32;
  int tx = threadIdx.x, ty = threadIdx.y;  // 32 x 8
#pragma unroll
  for (int i = 0; i < 32; i += 8) {
    long idx = (long)(r0 + ty + i) * cols + c0 + tx;
    tile[ty + i][tx] = fm ? (float)((const bf16*)in)[idx] : ((const float*)in)[idx];
  }
  __syncthreads();
#pragma unroll
  for (int i = 0; i < 32; i += 8)
    out[(long)(c0 + ty + i) * 2048 + r0 + tx] = (bf16)tile[tx][ty + i];
}

// ---------------- generic transpose (+dtype-adaptive read) for Wo ----------------
__global__ __launch_bounds__(256) void transpose_cvt(
    const void* __restrict__ in, bf16* __restrict__ out,
    long in_stride, long out_stride, const int* __restrict__ flag) {
  __shared__ float tile[32][33];
  int fm = *flag;
  int c0 = blockIdx.x * 32, r0 = blockIdx.y * 32;
  int tx = threadIdx.x, ty = threadIdx.y;
#pragma unroll
  for (int i = 0; i < 32; i += 8) {
    long idx = (long)(r0 + ty + i) * in_stride + c0 + tx;
    tile[ty + i][tx] = fm ? (float)((const bf16*)in)[idx] : ((const float*)in)[idx];
  }
  __syncthreads();
#pragma unroll
  for (int i = 0; i < 32; i += 8)
    out[(long)(c0 + ty + i) * out_stride + r0 + tx] = (bf16)tile[tx][ty + i];
}

// ---------------- GEMM: C = A * Bt^T ----------------
// Depth-2 pipeline (T3+T4): 3 LDS buffers; tile t's loads issued at iter t-2, so the
// wait for tile t is a counted s_waitcnt vmcnt(8) (two tiles = 8 VMEM ops allowed in
// flight) instead of a drain-to-0 -- never vmcnt(0) in the main loop (catalog T4).
// Raw s_barrier x2 per iter: barrier1 publishes tile t (after each wave's own counted
// vmcnt; per-wave wait THEN barrier => cross-wave visibility); barrier2 separates this
// iter's ds_reads of buf t%3 from iter t+1's re-stage of the same buffer (NBUF=3:
// stage(t+3) targets buf t%3).
// fp32-A path (gemm1 when x is fp32): A via float4->VGPR, convert deferred one
// iteration (T14 split) so the loads land under the MFMAs; the compiler's own wait on
// the float data transitively guarantees the earlier-issued B-DMA completed (vmcnt
// completion is in-order), plus belt vmcnt(12)+lgkmcnt(0) at the publish barrier.
// T1 XCD swizzle kept (FETCH_SIZE 155->69 MB measured). Assumes K/BK >= 3.
#define BM 128
#define BN 128
#define BK 32

__global__ __launch_bounds__(256) void gemm_bt(
    const void* __restrict__ A, const bf16* __restrict__ Bt, void* __restrict__ C,
    int M, int N, int K, int ldc, int ncmax,
    bf16* __restrict__ vt_out, int vcol0,
    const int* __restrict__ flag, int adyn, int cdyn) {
  alignas(16) __shared__ bf16 la[3 * BM * BK];  // 3 x 8 KB, unpadded (DMA lane-linear)
  alignas(16) __shared__ bf16 lb[3 * BN * BK];  // 3 x 8 KB  (48 KB total: 3 blocks/CU)
  int fm = flag ? *flag : 1;
  bool af32 = adyn && !fm;
  bool cf32 = cdyn && !fm;
  int tid = threadIdx.x;
  int wave = tid >> 6, lane = tid & 63;
  int wr = wave >> 1, wc = wave & 1;
  int quad = lane >> 4, l16 = lane & 15;

  // T1: XCD-aware block swizzle (nwg % 8 == 0 for both launches)
  int nwg = (int)(gridDim.x * gridDim.y);
  int flat = (int)(blockIdx.y * gridDim.x + blockIdx.x);
  int cpx = nwg >> 3;
  int wk = (flat & 7) * cpx + (flat >> 3);
  int bx = wk % (int)gridDim.x, by = wk / (int)gridDim.x;
  int m0 = by * BM, n0 = bx * BN;

  f32x4 acc[4][4] = {};

  // DMA coords: lane covers row (wave*16 + lane/4), 8-elem chunk (lane%4)
  int sr = (wave << 4) + (lane >> 2);
  int sc = (lane & 3) << 3;
  const bf16* gb0 = Bt + (long)(n0 + sr) * K + sc;
  const bf16* gb1 = Bt + (long)(n0 + 64 + sr) * K + sc;
  int lo0 = (wave << 9);          // wave-uniform LDS staging offsets (elems)
  int lo1 = 2048 + (wave << 9);
  const bf16* ga0 = nullptr; const bf16* ga1 = nullptr;
  const float* gaf = nullptr;
  int fr = tid >> 1, fh = (tid & 1) << 4;  // fp32-A path: row, 16-elem half
  if (af32) gaf = (const float*)A + (long)(m0 + fr) * K + fh;
  else { ga0 = (const bf16*)A + (long)(m0 + sr) * K + sc;
         ga1 = (const bf16*)A + (long)(m0 + 64 + sr) * K + sc; }
  int lawo = fr * BK + fh;  // af32 ds_write offset within buffer

  int nk = K / BK;  // 64 at both call sites; pipeline assumes nk >= 3

  auto stageB = [&](int T, int buf) {
    int k0 = T * BK;
    bf16* d = lb + (buf << 12);
    gload16(gb0 + k0, d + lo0);
    gload16(gb1 + k0, d + lo1);
  };
  auto stageA = [&](int T, int buf) {
    int k0 = T * BK;
    bf16* d = la + (buf << 12);
    gload16(ga0 + k0, d + lo0);
    gload16(ga1 + k0, d + lo1);
  };
  auto loadA = [&](int T, float4* f) {
    const float* fp = gaf + (long)T * BK;
#pragma unroll
    for (int u = 0; u < 4; u++) f[u] = *(const float4*)(fp + 4 * u);
  };
  auto cvtwrite = [&](const float4* f, int buf) {
    alignas(16) bf16 tt[16];
#pragma unroll
    for (int u = 0; u < 4; u++) {
      tt[4 * u] = (bf16)f[u].x; tt[4 * u + 1] = (bf16)f[u].y;
      tt[4 * u + 2] = (bf16)f[u].z; tt[4 * u + 3] = (bf16)f[u].w;
    }
    bf16* d = la + (buf << 12) + lawo;
    *(uint4*)d = *(uint4*)tt;
    *(uint4*)(d + 8) = *(uint4*)(tt + 8);
  };
  auto compute = [&](int buf) {
    const bf16* pa = la + (buf << 12) + ((wr << 6) + l16) * BK + (quad << 3);
    const bf16* pb = lb + (buf << 12) + ((wc << 6) + l16) * BK + (quad << 3);
    bf16x8 afr[4], bfr[4];
#pragma unroll
    for (int i = 0; i < 4; i++) afr[i] = *(const bf16x8*)(pa + (i << 4) * BK);
#pragma unroll
    for (int j = 0; j < 4; j++) bfr[j] = *(const bf16x8*)(pb + (j << 4) * BK);
#pragma unroll
    for (int i = 0; i < 4; i++)
#pragma unroll
      for (int j = 0; j < 4; j++)
        acc[i][j] = __builtin_amdgcn_mfma_f32_16x16x32_bf16(afr[i], bfr[j], acc[i][j], 0, 0, 0);
  };

  if (!af32) {
    // ---- bf16-A path: 4 DMA ops per tile; steady-state allowance = 2 tiles = 8 ----
    stageB(0, 0); stageA(0, 0);
    stageB(1, 1); stageA(1, 1);
    for (int t = 0; t + 2 < nk; ++t) {
      int bS = (t + 2) % 3, bC = t % 3;
      stageB(t + 2, bS);
      stageA(t + 2, bS);
      asm volatile("s_waitcnt vmcnt(8)" ::: "memory");  // tile t done; t+1,t+2 in flight
      __builtin_amdgcn_s_barrier();                     // publish tile t to all waves
      compute(bC);
      __builtin_amdgcn_s_barrier();                     // reads of bC done before restage
    }
    asm volatile("s_waitcnt vmcnt(4)" ::: "memory");    // tile nk-2 done
    __builtin_amdgcn_s_barrier();
    compute((nk - 2) % 3);
    asm volatile("s_waitcnt vmcnt(0)" ::: "memory");    // tile nk-1 done
    __builtin_amdgcn_s_barrier();
    compute((nk - 1) % 3);
  } else {
    // ---- fp32-A path: B via DMA, A via float4->regs, convert deferred 1 iter ----
    float4 fP[4], fN[4];
    stageB(0, 0); loadA(0, fP); cvtwrite(fP, 0);  // prologue waits are one-time
    stageB(1, 1); loadA(1, fP); cvtwrite(fP, 1);
    for (int t = 0; t + 2 < nk; ++t) {
      int bS = (t + 2) % 3, bC = t % 3;
      stageB(t + 2, bS);
      loadA(t + 2, fN);
      if (t > 0) cvtwrite(fP, (t + 1) % 3);  // A(t+1): loads landed during prev iter
      // belt: 12 = ops of iters t-1,t; compiler's fP-wait already implies B(t) done
      asm volatile("s_waitcnt vmcnt(12) lgkmcnt(0)" ::: "memory");
      __builtin_amdgcn_s_barrier();
      compute(bC);
      __builtin_amdgcn_s_barrier();
#pragma unroll
      for (int u = 0; u < 4; u++) fP[u] = fN[u];
    }
    cvtwrite(fP, (nk - 1) % 3);   // A(nk-1); ds_write latency hides under compute
    compute((nk - 2) % 3);        // published at last barrier1
    asm volatile("s_waitcnt vmcnt(0) lgkmcnt(0)" ::: "memory");
    __builtin_amdgcn_s_barrier();
    compute((nk - 1) % 3);
  }

  // C/D layout: col = lane&15, row = quad*4 + reg
  if (vt_out && n0 >= vcol0) {
    // V region of gemm1: write V^T[b][hd][s] directly (packed 8B stores)
#pragma unroll
    for (int i = 0; i < 4; i++)
#pragma unroll
      for (int j = 0; j < 4; j++) {
        int col = n0 + (wc << 6) + (j << 4) + l16;
        int hdg = col - vcol0;                            // 0..511 = kh*128+hd
        int row0 = m0 + (wr << 6) + (i << 4) + (quad << 2);
        int bb = row0 >> 11, s = row0 & 2047;             // row0 % 4 == 0: no b crossing
        ushort4 p;
        p.x = bfb(acc[i][j][0]); p.y = bfb(acc[i][j][1]);
        p.z = bfb(acc[i][j][2]); p.w = bfb(acc[i][j][3]);
        *(ushort4*)(vt_out + (((long)(bb * 512 + hdg)) << 11) + s) = p;
      }
  } else {
#pragma unroll
    for (int i = 0; i < 4; i++)
#pragma unroll
      for (int j = 0; j < 4; j++) {
        int col = n0 + (wc << 6) + (j << 4) + l16;
        if (col >= ncmax) continue;
#pragma unroll
        for (int r = 0; r < 4; r++) {
          long row = m0 + (wr << 6) + (i << 4) + (quad << 2) + r;
          float v = acc[i][j][r];
          if (cf32) ((float*)C)[row * ldc + col] = v;
          else      ((bf16*)C)[row * ldc + col] = (bf16)v;
        }
      }
  }
}

// ---------------- RoPE + scatter (Q pre-scaled by 1/sqrt(d)) ----------------
__global__ __launch_bounds__(256) void rope_scatter(
    const bf16* __restrict__ qkv, bf16* __restrict__ Q, bf16* __restrict__ Ko) {
  int row = blockIdx.x;  // b*S + s
  int b = row >> 11, s = row & 2047;
  int tid = threadIdx.x;
  const bf16* src = qkv + (long)row * QKW;
#pragma unroll
  for (int it = 0; it < 4; ++it) {
    int p = tid + it * 256;
    int h = p >> 6, i = p & 63;
    float x1 = (float)src[h * 128 + 2 * i];
    float x2 = (float)src[h * 128 + 2 * i + 1];
    float theta = __expf(-0.14391156831212787f * (float)i);  // 10000^(-2i/128)
    float sn, cs;
    sincosf((float)s * theta, &sn, &cs);
    long qb = ((long)(b * H_ + h) * S_ + s) * HD_;
    Q[qb + i]      = (bf16)((x1 * cs - x2 * sn) * SCALE);
    Q[qb + 64 + i] = (bf16)((x1 * sn + x2 * cs) * SCALE);
  }
  {
    int kh = tid >> 6, i = tid & 63;
    float x1 = (float)src[2048 + kh * 128 + 2 * i];
    float x2 = (float)src[2048 + kh * 128 + 2 * i + 1];
    float theta = __expf(-0.14391156831212787f * (float)i);
    float sn, cs;
    sincosf((float)s * theta, &sn, &cs);
    long kb = ((long)(b * HKV_ + kh) * S_ + s) * HD_;
    Ko[kb + i]      = (bf16)(x1 * cs - x2 * sn);
    Ko[kb + 64 + i] = (bf16)(x1 * sn + x2 * cs);
  }
}

// ---------------- flash attention ----------------
// S^T = K Q^T (lane l16 = qrow, regs = 4 keys) -> per-lane softmax -> PV straight from
// registers (S-accum == B-operand layout of v_mfma_f32_16x16x16bf16_1k). K/V staged by
// global_load_lds DMA (zero data VGPRs), double-buffered, XOR-swizzled per-lane SOURCE
// addressing so the lane-linear LDS image has conflict-free fragment reads.
// Causal load balance: block qt0 processes q-tiles {qt0, 31-qt0} -> every block does
// exactly 33 key-tiles; grid = 512 blocks = 2/CU (64KB LDS) -> one fully-resident,
// perfectly balanced pass. (DMA here is covered by ~48 MFMA + softmax per barrier, so
// the per-tile drain is already hidden -- unlike the GEMM's 16-MFMA phase.)
#define KTILE 8192  // 64 rows x 128 elems
#define VTILE 8192  // 128 rows x 64 elems

__global__ __launch_bounds__(256) void attn_kernel(
    const bf16* __restrict__ Q, const bf16* __restrict__ K,
    const bf16* __restrict__ Vt, bf16* __restrict__ O) {
  alignas(16) __shared__ bf16 Ks[2 * KTILE];  // 32 KB
  alignas(16) __shared__ bf16 Vs[2 * VTILE];  // 32 KB
  int qt0 = blockIdx.x;  // 0..15; paired with 31-qt0
  int h = blockIdx.y, b = blockIdx.z;
  int kh = h >> 2;
  int tid = threadIdx.x, wave = tid >> 6, lane = tid & 63;
  int quad = lane >> 4, l16 = lane & 15;
  const bf16* Kg = K + ((long)(b * HKV_ + kh) * S_) * HD_;
  const bf16* Vg = Vt + ((long)(b * HKV_ + kh) * HD_) * S_;

  // DMA source/dest offsets (elems). 16 calls/tile, call i = u*4+wave covers flat chunks
  // [i*64, i*64+64), chunk f: lane = f&63. K: r=f>>4, c=(f&15)^(r&15). V: v=f>>3, cv=(f&7)^(v&7).
  int kgo[4], vgo[4], klo[4], vlo[4];
#pragma unroll
  for (int u = 0; u < 4; u++) {
    int i = u * 4 + wave;
    int r = i * 4 + quad;                 // K row this lane fetches
    int c = l16 ^ (r & 15);               // swizzled chunk-in-row
    kgo[u] = r * HD_ + c * 8;
    klo[u] = i * 512;                     // wave-uniform LDS base (elems)
    int v = i * 8 + (lane >> 3);          // V^T row
    int cv = (lane & 7) ^ (v & 7);
    vgo[u] = v * S_ + cv * 8;
    vlo[u] = i * 512;
  }

  for (int hf = 0; hf < 2; ++hf) {
    int qt = hf ? 31 - qt0 : qt0;
    int q0 = qt * 64;
    const bf16* Qg = Q + ((long)(b * H_ + h) * S_ + q0) * HD_;

    // Q B-fragments in registers (pre-scaled by 1/sqrt(d)); lane l16 = qrow
    bf16x8 qb[4];
    {
      const bf16* qrow = Qg + (wave * 16 + l16) * HD_ + quad * 8;
#pragma unroll
      for (int kk = 0; kk < 4; kk++) qb[kk] = *(const bf16x8*)(qrow + kk * 32);
    }

    if (hf) __syncthreads();  // half-0 LDS readers done before re-preload of buf 0

    // preload tile 0 into buffer 0
#pragma unroll
    for (int u = 0; u < 4; u++) {
      gload16(Kg + kgo[u], Ks + klo[u]);
      gload16(Vg + vgo[u], Vs + vlo[u]);
    }

    f32x4 Of[8] = {};                   // O^T: col l16 = qrow, rows = hd
    float m_run = NEGINF, l_run = 0.f;  // per-lane state for qrow (wave*16 + l16)

    for (int kt = 0; kt <= qt; ++kt) {
      __syncthreads();  // drains DMA for buf (kt&1); prior readers of buf (kt&1)^1 done
      int p = kt & 1;
      if (kt < qt) {  // issue next-tile DMA into idle buffer; completes by next barrier
        const bf16* kn = Kg + (long)(kt + 1) * 8192;
        const bf16* vn = Vg + (long)(kt + 1) * 64;
        bf16* kd = Ks + (p ^ 1) * KTILE;
        bf16* vd = Vs + (p ^ 1) * VTILE;
#pragma unroll
        for (int u = 0; u < 4; u++) {
          gload16(kn + kgo[u], kd + klo[u]);
          gload16(vn + vgo[u], vd + vlo[u]);
        }
      }
      const bf16* kc = Ks + p * KTILE;
      const bf16* vc = Vs + p * VTILE;

      // S^T = K Q^T: A = K-frag (m = key), B = Q-frag (n = qrow)
      bool diag = (kt == qt);
      f32x4 sf[4];
      __builtin_amdgcn_s_setprio(1);  // T5: favor MFMA-issuing wave on the CU scheduler
#pragma unroll
      for (int jb = 0; jb < 4; jb++) {
        if (diag && jb > wave) {  // fully-masked key block on diagonal tile
          sf[jb] = (f32x4){NEGINF, NEGINF, NEGINF, NEGINF};
        } else {
          f32x4 a = {};
          const bf16* kbase = kc + (jb * 16 + l16) * 128;
#pragma unroll
          for (int kk = 0; kk < 4; kk++) {
            bf16x8 kf = *(const bf16x8*)(kbase + (((kk * 4 + quad) ^ l16) * 8));
            a = __builtin_amdgcn_mfma_f32_16x16x32_bf16(kf, qb[kk], a, 0, 0, 0);
          }
          sf[jb] = a;
        }
      }
      __builtin_amdgcn_s_setprio(0);
      if (diag) {  // partial mask on key block jb == wave (constant indices only)
#pragma unroll
        for (int jb = 0; jb < 4; jb++)
          if (jb == wave) {
#pragma unroll
            for (int r = 0; r < 4; r++)
              if (quad * 4 + r > l16) sf[jb][r] = NEGINF;
          }
      }

      // per-lane row max + 2 cross-quad shuffles
      float mx = NEGINF;
#pragma unroll
      for (int jb = 0; jb < 4; jb++)
#pragma unroll
        for (int r = 0; r < 4; r++) mx = fmaxf(mx, sf[jb][r]);
      mx = fmaxf(mx, __shfl_xor(mx, 16));
      mx = fmaxf(mx, __shfl_xor(mx, 32));
      // T13 defer-max: skip O-rescale while max grows <= 8 (P bounded by e^8, safe in
      // bf16/f32-accum; first tile always triggers since m_run = NEGINF)
      if (__any(mx > m_run + 8.0f)) {
        float mnew = fmaxf(m_run, mx);
        float alpha = __expf(m_run - mnew);
        m_run = mnew;
        l_run *= alpha;
#pragma unroll
        for (int n = 0; n < 8; n++) Of[n] *= alpha;
      }

      // p = exp(s - m): stays in registers as the PV B-operand
      float ls = 0.f;
      s16x4 pk[4];
#pragma unroll
      for (int jb = 0; jb < 4; jb++) {
        float p0 = __expf(sf[jb][0] - m_run);
        float p1 = __expf(sf[jb][1] - m_run);
        float p2 = __expf(sf[jb][2] - m_run);
        float p3 = __expf(sf[jb][3] - m_run);
        ls += (p0 + p1) + (p2 + p3);
        s16x4 t;
        t.x = (short)bfb(p0); t.y = (short)bfb(p1);
        t.z = (short)bfb(p2); t.w = (short)bfb(p3);
        pk[jb] = t;
      }
      l_run += ls;

      // O^T += V^T P^T via 16x16x16 MFMA (A = V^T frag from swizzled LDS, B = pk regs)
      __builtin_amdgcn_s_setprio(1);
#pragma unroll
      for (int jb = 0; jb < 4; jb++) {
        if (diag && jb > wave) continue;  // p == 0
#pragma unroll
        for (int n = 0; n < 8; n++) {
          int v = n * 16 + l16;
          const bf16* va_p = vc + v * 64 + (((jb * 2 + (quad >> 1)) ^ (l16 & 7)) * 8) + (quad & 1) * 4;
          s16x4 va = *(const s16x4*)va_p;
          Of[n] = __builtin_amdgcn_mfma_f32_16x16x16bf16_1k(va, pk[jb], Of[n], 0, 0, 0);
        }
      }
      __builtin_amdgcn_s_setprio(0);
    }

    // epilogue: reduce l across quads, packed 8B stores
    l_run += __shfl_xor(l_run, 16);
    l_run += __shfl_xor(l_run, 32);
    float inv = 1.0f / fmaxf(l_run, 1e-30f);
    bf16* Ob = O + ((long)(b * S_) + q0 + wave * 16 + l16) * D_ + h * HD_;
#pragma unroll
    for (int n = 0; n < 8; n++) {
      ushort4 w;
      w.x = bfb(Of[n][0] * inv); w.y = bfb(Of[n][1] * inv);
      w.z = bfb(Of[n][2] * inv); w.w = bfb(Of[n][3] * inv);
      *(ushort4*)(Ob + n * 16 + quad * 4) = w;
    }
  }
}

// ---------------- launch ----------------
extern "C" void kernel_launch(void* const* d_in, const int* in_sizes, int n_in,
                              void* d_out, int out_size, void* d_ws, size_t ws_size,
                              hipStream_t stream) {
  const void* x  = d_in[0];
  const void* Wq = d_in[1];
  const void* Wk = d_in[2];
  const void* Wv = d_in[3];
  const void* Wo = d_in[4];
  bf16* ws = (bf16*)d_ws;
  int* flag = (int*)d_ws;

  // workspace (bf16 elem offsets), peak 23,068,688 elems = 46.1 MB (proven)
  bf16* qkv   = ws + 16;        // 4096 x 2560          gemm1 -> rope
  bf16* Vtb   = ws + 10485776;  // 2 x 512 x 2048       gemm1 epilogue -> attn
  bf16* Qb    = ws + 12582928;  // 2x16x2048x128        rope -> attn
  bf16* wqkvT = ws + 12582928;  // 3072x2048 (overlaps Qb; dead before rope writes)
  bf16* Kb    = ws + 20971536;  // 2x4x2048x128         rope -> attn
  bf16* attno = ws + 16;        // reuse qkv            attn -> gemm2
  bf16* woT   = ws + 10485776;  // reuse Vtb/Qb region  (transposed after attn)

  dim3 tb(32, 8);
  detect_dtype<<<1, 256, 0, stream>>>((const unsigned*)x, flag);
  transpose_qkvw<<<dim3(64, 64, 3), tb, 0, stream>>>(Wq, Wk, Wv, wqkvT, flag);
  // qkv = x @ [Wq|Wk|Wv]; q,k cols -> qkv (ldc 2560), v cols -> Vtb transposed
  gemm_bt<<<dim3(QKVW / BN, (B_ * S_) / BM), 256, 0, stream>>>(
      x, wqkvT, qkv, B_ * S_, QKVW, D_, QKW, QKW, Vtb, QKW, flag, 1, 0);
  rope_scatter<<<B_ * S_, 256, 0, stream>>>(qkv, Qb, Kb);
  // paired-causal grid: 16 x 16 x 2 = 512 blocks, each does q-tiles {qt0, 31-qt0}
  attn_kernel<<<dim3(S_ / 128, H_, B_), 256, 0, stream>>>(Qb, Kb, Vtb, attno);
  transpose_cvt<<<dim3(64, 64, 1), tb, 0, stream>>>(Wo, woT, 2048, 2048, flag);
  // out = attno @ Wo (output dtype per flag)
  gemm_bt<<<dim3(D_ / BN, (B_ * S_) / BM), 256, 0, stream>>>(
      attno, woT, d_out, B_ * S_, D_, D_, D_, D_, nullptr, 0, flag, 0, 1);
}

// Round 5
// 432.999 us; speedup vs baseline: 1.0164x; 1.0164x over previous
//
#include <hip/hip_runtime.h>

typedef __bf16 bf16;
typedef __bf16 bf16x8 __attribute__((ext_vector_type(8)));
typedef float f32x4 __attribute__((ext_vector_type(4)));
typedef short s16x4 __attribute__((ext_vector_type(4)));

#define B_ 2
#define S_ 2048
#define D_ 2048
#define H_ 16
#define HKV_ 4
#define HD_ 128
#define QKVW 3072
#define QKW 2560                    // q+k columns (V handled separately)
#define SCALE 0.08838834764831845f  // 1/sqrt(128)
#define NEGINF -30000.0f            // finite -inf: exp underflows to 0, no inf-inf

// async global->LDS DMA, 16B per lane; LDS dest = wave-uniform base + lane*16
__device__ inline void gload16(const void* g, void* l) {
  __builtin_amdgcn_global_load_lds((const __attribute__((address_space(1))) unsigned int*)g,
                                   (__attribute__((address_space(3))) unsigned int*)l, 16, 0, 0);
}

__device__ inline unsigned short bfb(float v) {
  union { bf16 h; unsigned short u; } c;
  c.h = (bf16)v;
  return c.u;
}

// ---------------- dtype detection: bf16 or fp32 inputs? ----------------
__global__ void detect_dtype(const unsigned* __restrict__ xw, int* __restrict__ flag) {
  __shared__ int cnt;
  if (threadIdx.x == 0) cnt = 0;
  __syncthreads();
  unsigned w = xw[(size_t)threadIdx.x * 16384];
  unsigned low = w & 0xFFFFu;
  int e = (int)((low >> 7) & 0xFF);
  int vote = (low == 0u || (e >= 100 && e <= 140)) ? 1 : 0;
  atomicAdd(&cnt, vote);
  __syncthreads();
  if (threadIdx.x == 0) *flag = (cnt >= 128) ? 1 : 0;  // 1 = bf16, 0 = fp32
}

// ---------------- fused Wq/Wk/Wv transpose -> wqkvT (B^T layout) ----------------
__global__ __launch_bounds__(256) void transpose_qkvw(
    const void* __restrict__ Wq, const void* __restrict__ Wk, const void* __restrict__ Wv,
    bf16* __restrict__ wqkvT, const int* __restrict__ flag) {
  int z = blockIdx.z;
  const void* in = (z == 0) ? Wq : (z == 1) ? Wk : Wv;
  int cols = (z == 0) ? 2048 : 512;
  bf16* out = wqkvT + ((z == 0) ? 0 : (z == 1) ? 2048 * 2048 : 2560 * 2048);
  if (blockIdx.x * 32 >= cols) return;
  int fm = *flag;
  __shared__ float tile[32][33];
  int c0 = blockIdx.x * 32, r0 = blockIdx.y * 32;
  int tx = threadIdx.x, ty = threadIdx.y;  // 32 x 8
#pragma unroll
  for (int i = 0; i < 32; i += 8) {
    long idx = (long)(r0 + ty + i) * cols + c0 + tx;
    tile[ty + i][tx] = fm ? (float)((const bf16*)in)[idx] : ((const float*)in)[idx];
  }
  __syncthreads();
#pragma unroll
  for (int i = 0; i < 32; i += 8)
    out[(long)(c0 + ty + i) * 2048 + r0 + tx] = (bf16)tile[tx][ty + i];
}

// ---------------- generic transpose (+dtype-adaptive read) for Wo ----------------
__global__ __launch_bounds__(256) void transpose_cvt(
    const void* __restrict__ in, bf16* __restrict__ out,
    long in_stride, long out_stride, const int* __restrict__ flag) {
  __shared__ float tile[32][33];
  int fm = *flag;
  int c0 = blockIdx.x * 32, r0 = blockIdx.y * 32;
  int tx = threadIdx.x, ty = threadIdx.y;
#pragma unroll
  for (int i = 0; i < 32; i += 8) {
    long idx = (long)(r0 + ty + i) * in_stride + c0 + tx;
    tile[ty + i][tx] = fm ? (float)((const bf16*)in)[idx] : ((const float*)in)[idx];
  }
  __syncthreads();
#pragma unroll
  for (int i = 0; i < 32; i += 8)
    out[(long)(c0 + ty + i) * out_stride + r0 + tx] = (bf16)tile[tx][ty + i];
}

// ---------------- GEMM: C = A * Bt^T ----------------
// 2-phase double-buffer (R3 structure, reverted from the R4 coarse-depth-2 regression),
// with BK 32->64: halves the barrier-drain count, doubles MFMA per phase (32/wave).
// BK=64 => [128][64] bf16 tiles: linear layout would be a 16-way bank conflict on the
// 128B-stride fragment reads (m201's exact case), so tiles are XOR-swizzled BOTH sides
// (rule #21): LDS slot (r,c) holds global chunk c^(r&7); DMA *source* addresses carry
// the inverse permutation (LDS dest stays lane-linear as global_load_lds requires);
// fragment reads address chunk (kk*4+quad)^(l16&7) -> 2-way residual (free, m136).
// fp32-A path (gemm1, x is fp32): float4 loads issued at phase start, cvt+swizzled
// ds_write after the MFMAs (T14 split). T1 XCD swizzle kept (FETCH 155->69 MB).
#define BM 128
#define BN 128
#define BK 64

__global__ __launch_bounds__(256) void gemm_bt(
    const void* __restrict__ A, const bf16* __restrict__ Bt, void* __restrict__ C,
    int M, int N, int K, int ldc, int ncmax,
    bf16* __restrict__ vt_out, int vcol0,
    const int* __restrict__ flag, int adyn, int cdyn) {
  alignas(16) __shared__ bf16 la[2 * BM * BK];  // 2 x 16 KB
  alignas(16) __shared__ bf16 lb[2 * BN * BK];  // 2 x 16 KB -> 64 KB total (2 blocks/CU)
  int fm = flag ? *flag : 1;
  bool af32 = adyn && !fm;
  bool cf32 = cdyn && !fm;
  int tid = threadIdx.x;
  int wave = tid >> 6, lane = tid & 63;
  int wr = wave >> 1, wc = wave & 1;
  int quad = lane >> 4, l16 = lane & 15;

  // T1: XCD-aware block swizzle (nwg % 8 == 0 for both launches)
  int nwg = (int)(gridDim.x * gridDim.y);
  int flat = (int)(blockIdx.y * gridDim.x + blockIdx.x);
  int cpx = nwg >> 3;
  int wk = (flat & 7) * cpx + (flat >> 3);
  int bx = wk % (int)gridDim.x, by = wk / (int)gridDim.x;
  int m0 = by * BM, n0 = bx * BN;

  f32x4 acc[4][4] = {};

  // DMA coords: 4 instrs/wave/tile; instr u covers rows rb..rb+7 (rb = wave*32+u*8),
  // lane -> row rb+(lane>>3), LDS slot chunk lane&7; source chunk (lane&7)^(lane>>3).
  int drow = lane >> 3;
  int dchunk = ((lane & 7) ^ drow) << 3;  // source col offset (elems)
  long gbo[4], gao[4];
  int ldsb[4];
#pragma unroll
  for (int u = 0; u < 4; u++) {
    int rb = (wave << 5) + (u << 3);
    int sr = rb + drow;
    gbo[u] = (long)(n0 + sr) * K + dchunk;
    gao[u] = (long)(m0 + sr) * K + dchunk;
    ldsb[u] = rb << 6;  // rb*64 elems (lane-linear dest)
  }
  const float* gaf = nullptr;
  int fr = tid >> 1, fh = (tid & 1) << 5;  // fp32-A: row, 32-elem half
  if (af32) gaf = (const float*)A + (long)(m0 + fr) * K + fh;

  int nk = K / BK;  // 32 at both call sites

  auto stageB = [&](int k0, bf16* dst) {
#pragma unroll
    for (int u = 0; u < 4; u++) gload16(Bt + gbo[u] + k0, dst + ldsb[u]);
  };
  auto stageA = [&](int k0, bf16* dst) {
    const bf16* Ab = (const bf16*)A;
#pragma unroll
    for (int u = 0; u < 4; u++) gload16(Ab + gao[u] + k0, dst + ldsb[u]);
  };
  auto loadA = [&](int k0, float4* f) {
    const float* fp = gaf + k0;
#pragma unroll
    for (int u = 0; u < 8; u++) f[u] = *(const float4*)(fp + 4 * u);
  };
  auto cvtwrite = [&](const float4* f, bf16* dbuf) {
    int g = fr & 7, h4 = (tid & 1) << 2;
    bf16* row = dbuf + (fr << 6);
#pragma unroll
    for (int cc = 0; cc < 4; cc++) {
      alignas(16) bf16 tt[8];
      float4 a = f[2 * cc], b2 = f[2 * cc + 1];
      tt[0] = (bf16)a.x;  tt[1] = (bf16)a.y;  tt[2] = (bf16)a.z;  tt[3] = (bf16)a.w;
      tt[4] = (bf16)b2.x; tt[5] = (bf16)b2.y; tt[6] = (bf16)b2.z; tt[7] = (bf16)b2.w;
      *(uint4*)(row + (((h4 + cc) ^ g) << 3)) = *(uint4*)tt;
    }
  };
  auto compute = [&](int buf) {
    const bf16* pa = la + (buf << 13) + l16 * 64;
    const bf16* pb = lb + (buf << 13) + l16 * 64;
    int s7 = l16 & 7;
#pragma unroll
    for (int kk = 0; kk < 2; kk++) {
      int co = (((kk << 2) + quad) ^ s7) << 3;  // swizzled chunk offset
      bf16x8 afr[4], bfr[4];
#pragma unroll
      for (int i = 0; i < 4; i++)
        afr[i] = *(const bf16x8*)(pa + (((wr << 6) + (i << 4)) << 6) + co);
#pragma unroll
      for (int j = 0; j < 4; j++)
        bfr[j] = *(const bf16x8*)(pb + (((wc << 6) + (j << 4)) << 6) + co);
#pragma unroll
      for (int i = 0; i < 4; i++)
#pragma unroll
        for (int j = 0; j < 4; j++)
          acc[i][j] = __builtin_amdgcn_mfma_f32_16x16x32_bf16(afr[i], bfr[j], acc[i][j], 0, 0, 0);
    }
  };

  // ---- prologue: stage tile 0 into buffer 0 ----
  stageB(0, lb);
  if (af32) {
    float4 f0[8];
    loadA(0, f0);
    cvtwrite(f0, la);
  } else {
    stageA(0, la);
  }
  __syncthreads();

  // ---- main loop: ONE barrier per K-step; stage t+1 overlaps compute t ----
  if (!af32) {
    for (int t = 0; t < nk; ++t) {
      int cur = t & 1, nxt = cur ^ 1;
      if (t + 1 < nk) {
        int k0 = (t + 1) * BK;
        stageB(k0, lb + (nxt << 13));
        stageA(k0, la + (nxt << 13));
      }
      compute(cur);
      __syncthreads();  // drains DMA (next tile ready); readers of cur done
    }
  } else {
    for (int t = 0; t < nk; ++t) {
      int cur = t & 1, nxt = cur ^ 1;
      float4 f[8];
      if (t + 1 < nk) {
        int k0 = (t + 1) * BK;
        stageB(k0, lb + (nxt << 13));
        loadA(k0, f);
      }
      compute(cur);
      if (t + 1 < nk) cvtwrite(f, la + (nxt << 13));  // loads landed during MFMA
      __syncthreads();
    }
  }

  // C/D layout: col = lane&15, row = quad*4 + reg
  if (vt_out && n0 >= vcol0) {
    // V region of gemm1: write V^T[b][hd][s] directly (packed 8B stores)
#pragma unroll
    for (int i = 0; i < 4; i++)
#pragma unroll
      for (int j = 0; j < 4; j++) {
        int col = n0 + (wc << 6) + (j << 4) + l16;
        int hdg = col - vcol0;                            // 0..511 = kh*128+hd
        int row0 = m0 + (wr << 6) + (i << 4) + (quad << 2);
        int bb = row0 >> 11, s = row0 & 2047;             // row0 % 4 == 0: no b crossing
        ushort4 p;
        p.x = bfb(acc[i][j][0]); p.y = bfb(acc[i][j][1]);
        p.z = bfb(acc[i][j][2]); p.w = bfb(acc[i][j][3]);
        *(ushort4*)(vt_out + (((long)(bb * 512 + hdg)) << 11) + s) = p;
      }
  } else {
#pragma unroll
    for (int i = 0; i < 4; i++)
#pragma unroll
      for (int j = 0; j < 4; j++) {
        int col = n0 + (wc << 6) + (j << 4) + l16;
        if (col >= ncmax) continue;
#pragma unroll
        for (int r = 0; r < 4; r++) {
          long row = m0 + (wr << 6) + (i << 4) + (quad << 2) + r;
          float v = acc[i][j][r];
          if (cf32) ((float*)C)[row * ldc + col] = v;
          else      ((bf16*)C)[row * ldc + col] = (bf16)v;
        }
      }
  }
}

// ---------------- RoPE + scatter (Q pre-scaled by 1/sqrt(d)) ----------------
__global__ __launch_bounds__(256) void rope_scatter(
    const bf16* __restrict__ qkv, bf16* __restrict__ Q, bf16* __restrict__ Ko) {
  int row = blockIdx.x;  // b*S + s
  int b = row >> 11, s = row & 2047;
  int tid = threadIdx.x;
  const bf16* src = qkv + (long)row * QKW;
#pragma unroll
  for (int it = 0; it < 4; ++it) {
    int p = tid + it * 256;
    int h = p >> 6, i = p & 63;
    float x1 = (float)src[h * 128 + 2 * i];
    float x2 = (float)src[h * 128 + 2 * i + 1];
    float theta = __expf(-0.14391156831212787f * (float)i);  // 10000^(-2i/128)
    float sn, cs;
    sincosf((float)s * theta, &sn, &cs);
    long qb = ((long)(b * H_ + h) * S_ + s) * HD_;
    Q[qb + i]      = (bf16)((x1 * cs - x2 * sn) * SCALE);
    Q[qb + 64 + i] = (bf16)((x1 * sn + x2 * cs) * SCALE);
  }
  {
    int kh = tid >> 6, i = tid & 63;
    float x1 = (float)src[2048 + kh * 128 + 2 * i];
    float x2 = (float)src[2048 + kh * 128 + 2 * i + 1];
    float theta = __expf(-0.14391156831212787f * (float)i);
    float sn, cs;
    sincosf((float)s * theta, &sn, &cs);
    long kb = ((long)(b * HKV_ + kh) * S_ + s) * HD_;
    Ko[kb + i]      = (bf16)(x1 * cs - x2 * sn);
    Ko[kb + 64 + i] = (bf16)(x1 * sn + x2 * cs);
  }
}

// ---------------- flash attention ----------------
// S^T = K Q^T (lane l16 = qrow, regs = 4 keys) -> per-lane softmax -> PV straight from
// registers (S-accum == B-operand layout of v_mfma_f32_16x16x16bf16_1k). K/V staged by
// global_load_lds DMA (zero data VGPRs), double-buffered, XOR-swizzled per-lane SOURCE
// addressing so the lane-linear LDS image has conflict-free fragment reads.
// Causal load balance: block qt0 processes q-tiles {qt0, 31-qt0} -> every block does
// exactly 33 key-tiles; grid = 512 blocks = 2/CU (64KB LDS) -> one fully-resident,
// perfectly balanced pass. (DMA here is covered by ~48 MFMA + softmax per barrier.)
#define KTILE 8192  // 64 rows x 128 elems
#define VTILE 8192  // 128 rows x 64 elems

__global__ __launch_bounds__(256) void attn_kernel(
    const bf16* __restrict__ Q, const bf16* __restrict__ K,
    const bf16* __restrict__ Vt, bf16* __restrict__ O) {
  alignas(16) __shared__ bf16 Ks[2 * KTILE];  // 32 KB
  alignas(16) __shared__ bf16 Vs[2 * VTILE];  // 32 KB
  int qt0 = blockIdx.x;  // 0..15; paired with 31-qt0
  int h = blockIdx.y, b = blockIdx.z;
  int kh = h >> 2;
  int tid = threadIdx.x, wave = tid >> 6, lane = tid & 63;
  int quad = lane >> 4, l16 = lane & 15;
  const bf16* Kg = K + ((long)(b * HKV_ + kh) * S_) * HD_;
  const bf16* Vg = Vt + ((long)(b * HKV_ + kh) * HD_) * S_;

  // DMA source/dest offsets (elems). 16 calls/tile, call i = u*4+wave covers flat chunks
  // [i*64, i*64+64), chunk f: lane = f&63. K: r=f>>4, c=(f&15)^(r&15). V: v=f>>3, cv=(f&7)^(v&7).
  int kgo[4], vgo[4], klo[4], vlo[4];
#pragma unroll
  for (int u = 0; u < 4; u++) {
    int i = u * 4 + wave;
    int r = i * 4 + quad;                 // K row this lane fetches
    int c = l16 ^ (r & 15);               // swizzled chunk-in-row
    kgo[u] = r * HD_ + c * 8;
    klo[u] = i * 512;                     // wave-uniform LDS base (elems)
    int v = i * 8 + (lane >> 3);          // V^T row
    int cv = (lane & 7) ^ (v & 7);
    vgo[u] = v * S_ + cv * 8;
    vlo[u] = i * 512;
  }

  for (int hf = 0; hf < 2; ++hf) {
    int qt = hf ? 31 - qt0 : qt0;
    int q0 = qt * 64;
    const bf16* Qg = Q + ((long)(b * H_ + h) * S_ + q0) * HD_;

    // Q B-fragments in registers (pre-scaled by 1/sqrt(d)); lane l16 = qrow
    bf16x8 qb[4];
    {
      const bf16* qrow = Qg + (wave * 16 + l16) * HD_ + quad * 8;
#pragma unroll
      for (int kk = 0; kk < 4; kk++) qb[kk] = *(const bf16x8*)(qrow + kk * 32);
    }

    if (hf) __syncthreads();  // half-0 LDS readers done before re-preload of buf 0

    // preload tile 0 into buffer 0
#pragma unroll
    for (int u = 0; u < 4; u++) {
      gload16(Kg + kgo[u], Ks + klo[u]);
      gload16(Vg + vgo[u], Vs + vlo[u]);
    }

    f32x4 Of[8] = {};                   // O^T: col l16 = qrow, rows = hd
    float m_run = NEGINF, l_run = 0.f;  // per-lane state for qrow (wave*16 + l16)

    for (int kt = 0; kt <= qt; ++kt) {
      __syncthreads();  // drains DMA for buf (kt&1); prior readers of buf (kt&1)^1 done
      int p = kt & 1;
      if (kt < qt) {  // issue next-tile DMA into idle buffer; completes by next barrier
        const bf16* kn = Kg + (long)(kt + 1) * 8192;
        const bf16* vn = Vg + (long)(kt + 1) * 64;
        bf16* kd = Ks + (p ^ 1) * KTILE;
        bf16* vd = Vs + (p ^ 1) * VTILE;
#pragma unroll
        for (int u = 0; u < 4; u++) {
          gload16(kn + kgo[u], kd + klo[u]);
          gload16(vn + vgo[u], vd + vlo[u]);
        }
      }
      const bf16* kc = Ks + p * KTILE;
      const bf16* vc = Vs + p * VTILE;

      // S^T = K Q^T: A = K-frag (m = key), B = Q-frag (n = qrow)
      bool diag = (kt == qt);
      f32x4 sf[4];
      __builtin_amdgcn_s_setprio(1);  // T5: favor MFMA-issuing wave on the CU scheduler
#pragma unroll
      for (int jb = 0; jb < 4; jb++) {
        if (diag && jb > wave) {  // fully-masked key block on diagonal tile
          sf[jb] = (f32x4){NEGINF, NEGINF, NEGINF, NEGINF};
        } else {
          f32x4 a = {};
          const bf16* kbase = kc + (jb * 16 + l16) * 128;
#pragma unroll
          for (int kk = 0; kk < 4; kk++) {
            bf16x8 kf = *(const bf16x8*)(kbase + (((kk * 4 + quad) ^ l16) * 8));
            a = __builtin_amdgcn_mfma_f32_16x16x32_bf16(kf, qb[kk], a, 0, 0, 0);
          }
          sf[jb] = a;
        }
      }
      __builtin_amdgcn_s_setprio(0);
      if (diag) {  // partial mask on key block jb == wave (constant indices only)
#pragma unroll
        for (int jb = 0; jb < 4; jb++)
          if (jb == wave) {
#pragma unroll
            for (int r = 0; r < 4; r++)
              if (quad * 4 + r > l16) sf[jb][r] = NEGINF;
          }
      }

      // per-lane row max + 2 cross-quad shuffles
      float mx = NEGINF;
#pragma unroll
      for (int jb = 0; jb < 4; jb++)
#pragma unroll
        for (int r = 0; r < 4; r++) mx = fmaxf(mx, sf[jb][r]);
      mx = fmaxf(mx, __shfl_xor(mx, 16));
      mx = fmaxf(mx, __shfl_xor(mx, 32));
      // T13 defer-max: skip O-rescale while max grows <= 8 (P bounded by e^8, safe in
      // bf16/f32-accum; first tile always triggers since m_run = NEGINF)
      if (__any(mx > m_run + 8.0f)) {
        float mnew = fmaxf(m_run, mx);
        float alpha = __expf(m_run - mnew);
        m_run = mnew;
        l_run *= alpha;
#pragma unroll
        for (int n = 0; n < 8; n++) Of[n] *= alpha;
      }

      // p = exp(s - m): stays in registers as the PV B-operand
      float ls = 0.f;
      s16x4 pk[4];
#pragma unroll
      for (int jb = 0; jb < 4; jb++) {
        float p0 = __expf(sf[jb][0] - m_run);
        float p1 = __expf(sf[jb][1] - m_run);
        float p2 = __expf(sf[jb][2] - m_run);
        float p3 = __expf(sf[jb][3] - m_run);
        ls += (p0 + p1) + (p2 + p3);
        s16x4 t;
        t.x = (short)bfb(p0); t.y = (short)bfb(p1);
        t.z = (short)bfb(p2); t.w = (short)bfb(p3);
        pk[jb] = t;
      }
      l_run += ls;

      // O^T += V^T P^T via 16x16x16 MFMA (A = V^T frag from swizzled LDS, B = pk regs)
      __builtin_amdgcn_s_setprio(1);
#pragma unroll
      for (int jb = 0; jb < 4; jb++) {
        if (diag && jb > wave) continue;  // p == 0
#pragma unroll
        for (int n = 0; n < 8; n++) {
          int v = n * 16 + l16;
          const bf16* va_p = vc + v * 64 + (((jb * 2 + (quad >> 1)) ^ (l16 & 7)) * 8) + (quad & 1) * 4;
          s16x4 va = *(const s16x4*)va_p;
          Of[n] = __builtin_amdgcn_mfma_f32_16x16x16bf16_1k(va, pk[jb], Of[n], 0, 0, 0);
        }
      }
      __builtin_amdgcn_s_setprio(0);
    }

    // epilogue: reduce l across quads, packed 8B stores
    l_run += __shfl_xor(l_run, 16);
    l_run += __shfl_xor(l_run, 32);
    float inv = 1.0f / fmaxf(l_run, 1e-30f);
    bf16* Ob = O + ((long)(b * S_) + q0 + wave * 16 + l16) * D_ + h * HD_;
#pragma unroll
    for (int n = 0; n < 8; n++) {
      ushort4 w;
      w.x = bfb(Of[n][0] * inv); w.y = bfb(Of[n][1] * inv);
      w.z = bfb(Of[n][2] * inv); w.w = bfb(Of[n][3] * inv);
      *(ushort4*)(Ob + n * 16 + quad * 4) = w;
    }
  }
}

// ---------------- launch ----------------
extern "C" void kernel_launch(void* const* d_in, const int* in_sizes, int n_in,
                              void* d_out, int out_size, void* d_ws, size_t ws_size,
                              hipStream_t stream) {
  const void* x  = d_in[0];
  const void* Wq = d_in[1];
  const void* Wk = d_in[2];
  const void* Wv = d_in[3];
  const void* Wo = d_in[4];
  bf16* ws = (bf16*)d_ws;
  int* flag = (int*)d_ws;

  // workspace (bf16 elem offsets), peak 23,068,688 elems = 46.1 MB (proven)
  bf16* qkv   = ws + 16;        // 4096 x 2560          gemm1 -> rope
  bf16* Vtb   = ws + 10485776;  // 2 x 512 x 2048       gemm1 epilogue -> attn
  bf16* Qb    = ws + 12582928;  // 2x16x2048x128        rope -> attn
  bf16* wqkvT = ws + 12582928;  // 3072x2048 (overlaps Qb; dead before rope writes)
  bf16* Kb    = ws + 20971536;  // 2x4x2048x128         rope -> attn
  bf16* attno = ws + 16;        // reuse qkv            attn -> gemm2
  bf16* woT   = ws + 10485776;  // reuse Vtb/Qb region  (transposed after attn)

  dim3 tb(32, 8);
  detect_dtype<<<1, 256, 0, stream>>>((const unsigned*)x, flag);
  transpose_qkvw<<<dim3(64, 64, 3), tb, 0, stream>>>(Wq, Wk, Wv, wqkvT, flag);
  // qkv = x @ [Wq|Wk|Wv]; q,k cols -> qkv (ldc 2560), v cols -> Vtb transposed
  gemm_bt<<<dim3(QKVW / BN, (B_ * S_) / BM), 256, 0, stream>>>(
      x, wqkvT, qkv, B_ * S_, QKVW, D_, QKW, QKW, Vtb, QKW, flag, 1, 0);
  rope_scatter<<<B_ * S_, 256, 0, stream>>>(qkv, Qb, Kb);
  // paired-causal grid: 16 x 16 x 2 = 512 blocks, each does q-tiles {qt0, 31-qt0}
  attn_kernel<<<dim3(S_ / 128, H_, B_), 256, 0, stream>>>(Qb, Kb, Vtb, attno);
  transpose_cvt<<<dim3(64, 64, 1), tb, 0, stream>>>(Wo, woT, 2048, 2048, flag);
  // out = attno @ Wo (output dtype per flag)
  gemm_bt<<<dim3(D_ / BN, (B_ * S_) / BM), 256, 0, stream>>>(
      attno, woT, d_out, B_ * S_, D_, D_, D_, D_, nullptr, 0, flag, 0, 1);
}

// Round 6
// 398.624 us; speedup vs baseline: 1.1040x; 1.0862x over previous
//
#include <hip/hip_runtime.h>

typedef __bf16 bf16;
typedef __bf16 bf16x8 __attribute__((ext_vector_type(8)));
typedef float f32x4 __attribute__((ext_vector_type(4)));
typedef short s16x4 __attribute__((ext_vector_type(4)));

#define B_ 2
#define S_ 2048
#define D_ 2048
#define H_ 16
#define HKV_ 4
#define HD_ 128
#define QKVW 3072
#define QKW 2560                    // q+k columns (V handled separately)
#define SCALE 0.08838834764831845f  // 1/sqrt(128)
#define NEGINF -30000.0f            // finite -inf: exp underflows to 0, no inf-inf

// async global->LDS DMA, 16B per lane; LDS dest = wave-uniform base + lane*16
__device__ inline void gload16(const void* g, void* l) {
  __builtin_amdgcn_global_load_lds((const __attribute__((address_space(1))) unsigned int*)g,
                                   (__attribute__((address_space(3))) unsigned int*)l, 16, 0, 0);
}

__device__ inline unsigned short bfb(float v) {
  union { bf16 h; unsigned short u; } c;
  c.h = (bf16)v;
  return c.u;
}

// barrier with compiler memory fences on both sides: no memory op (ds_read/ds_write/
// global_load_lds) may be moved across it by the scheduler
__device__ inline void bar() {
  asm volatile("" ::: "memory");
  __builtin_amdgcn_s_barrier();
  asm volatile("" ::: "memory");
}

// ---------------- dtype detection: bf16 or fp32 inputs? ----------------
__global__ void detect_dtype(const unsigned* __restrict__ xw, int* __restrict__ flag) {
  __shared__ int cnt;
  if (threadIdx.x == 0) cnt = 0;
  __syncthreads();
  unsigned w = xw[(size_t)threadIdx.x * 16384];
  unsigned low = w & 0xFFFFu;
  int e = (int)((low >> 7) & 0xFF);
  int vote = (low == 0u || (e >= 100 && e <= 140)) ? 1 : 0;
  atomicAdd(&cnt, vote);
  __syncthreads();
  if (threadIdx.x == 0) *flag = (cnt >= 128) ? 1 : 0;  // 1 = bf16, 0 = fp32
}

// ---------------- fused Wq/Wk/Wv transpose -> wqkvT (B^T layout) ----------------
__global__ __launch_bounds__(256) void transpose_qkvw(
    const void* __restrict__ Wq, const void* __restrict__ Wk, const void* __restrict__ Wv,
    bf16* __restrict__ wqkvT, const int* __restrict__ flag) {
  int z = blockIdx.z;
  const void* in = (z == 0) ? Wq : (z == 1) ? Wk : Wv;
  int cols = (z == 0) ? 2048 : 512;
  bf16* out = wqkvT + ((z == 0) ? 0 : (z == 1) ? 2048 * 2048 : 2560 * 2048);
  if (blockIdx.x * 32 >= cols) return;
  int fm = *flag;
  __shared__ float tile[32][33];
  int c0 = blockIdx.x * 32, r0 = blockIdx.y * 32;
  int tx = threadIdx.x, ty = threadIdx.y;  // 32 x 8
#pragma unroll
  for (int i = 0; i < 32; i += 8) {
    long idx = (long)(r0 + ty + i) * cols + c0 + tx;
    tile[ty + i][tx] = fm ? (float)((const bf16*)in)[idx] : ((const float*)in)[idx];
  }
  __syncthreads();
#pragma unroll
  for (int i = 0; i < 32; i += 8)
    out[(long)(c0 + ty + i) * 2048 + r0 + tx] = (bf16)tile[tx][ty + i];
}

// ---------------- generic transpose (+dtype-adaptive read) for Wo ----------------
__global__ __launch_bounds__(256) void transpose_cvt(
    const void* __restrict__ in, bf16* __restrict__ out,
    long in_stride, long out_stride, const int* __restrict__ flag) {
  __shared__ float tile[32][33];
  int fm = *flag;
  int c0 = blockIdx.x * 32, r0 = blockIdx.y * 32;
  int tx = threadIdx.x, ty = threadIdx.y;
#pragma unroll
  for (int i = 0; i < 32; i += 8) {
    long idx = (long)(r0 + ty + i) * in_stride + c0 + tx;
    tile[ty + i][tx] = fm ? (float)((const bf16*)in)[idx] : ((const float*)in)[idx];
  }
  __syncthreads();
#pragma unroll
  for (int i = 0; i < 32; i += 8)
    out[(long)(c0 + ty + i) * out_stride + r0 + tx] = (bf16)tile[tx][ty + i];
}

// ---------------- GEMM: C = A * Bt^T ----------------
// R3 geometry (BK=32, 2 x 16 KB LDS -- the proven co-residency/L2 sweet spot; R4/R5
// showed any occupancy loss doubles FETCH and loses more than the change gains).
// New loop skeleton only (T4 counted vmcnt at constant LDS):
//   phase t: { stage(t+1); s_waitcnt vmcnt(4)   <- retires stage(t), leaves stage(t+1)
//              bar();  compute(t);  bar(); }       in flight ACROSS the barrier
// so each tile's wait lands a full phase after its issue (~600 cyc cover vs R3's ~300),
// and the main loop never drains vmcnt to 0. Barrier #2 protects buffer re-stage
// (other waves' reads of buf t&1 finish before phase t+1 re-DMAs it).
// fp32-A path (gemm1 when x is fp32): float loads prefetched TWO phases ahead (fP/fN),
// cvt+ds_write deferred to after the MFMAs; steady-state vmcnt(6) retires exactly
// {B(t), F(t+1)}. Final phase peeled with vmcnt(0).
// T1 XCD swizzle kept (FETCH 155->69 MB measured at R3).
#define BM 128
#define BN 128
#define BK 32

__global__ __launch_bounds__(256) void gemm_bt(
    const void* __restrict__ A, const bf16* __restrict__ Bt, void* __restrict__ C,
    int M, int N, int K, int ldc, int ncmax,
    bf16* __restrict__ vt_out, int vcol0,
    const int* __restrict__ flag, int adyn, int cdyn) {
  alignas(16) __shared__ bf16 la[2 * BM * BK];  // 2 x 8 KB, unpadded (DMA lane-linear)
  alignas(16) __shared__ bf16 lb[2 * BN * BK];  // 2 x 8 KB
  int fm = flag ? *flag : 1;
  bool af32 = adyn && !fm;
  bool cf32 = cdyn && !fm;
  int tid = threadIdx.x;
  int wave = tid >> 6, lane = tid & 63;
  int wr = wave >> 1, wc = wave & 1;
  int quad = lane >> 4, l16 = lane & 15;

  // T1: XCD-aware block swizzle (nwg % 8 == 0 for both launches)
  int nwg = (int)(gridDim.x * gridDim.y);
  int flat = (int)(blockIdx.y * gridDim.x + blockIdx.x);
  int cpx = nwg >> 3;
  int wk = (flat & 7) * cpx + (flat >> 3);
  int bx = wk % (int)gridDim.x, by = wk / (int)gridDim.x;
  int m0 = by * BM, n0 = bx * BN;

  f32x4 acc[4][4] = {};

  // DMA coords: lane covers row (wave*16 + lane/4), 8-elem chunk (lane%4)
  int sr = (wave << 4) + (lane >> 2);
  int sc = (lane & 3) << 3;
  const bf16* gb0 = Bt + (long)(n0 + sr) * K + sc;
  const bf16* gb1 = Bt + (long)(n0 + 64 + sr) * K + sc;
  int lo0 = (wave << 9);          // wave-uniform LDS staging offsets (elems)
  int lo1 = 2048 + (wave << 9);
  const bf16* ga0 = nullptr; const bf16* ga1 = nullptr;
  const float* gaf = nullptr;
  int fr = tid >> 1, fh = (tid & 1) << 4;  // fp32-A path: row, 16-elem half
  if (af32) gaf = (const float*)A + (long)(m0 + fr) * K + fh;
  else { ga0 = (const bf16*)A + (long)(m0 + sr) * K + sc;
         ga1 = (const bf16*)A + (long)(m0 + 64 + sr) * K + sc; }
  int lawo = fr * BK + fh;  // af32 ds_write offset within buffer

  int nk = K / BK;  // 64 at both call sites

  auto stageB = [&](int T, int buf) {
    int k0 = T * BK;
    bf16* d = lb + (buf << 12);
    gload16(gb0 + k0, d + lo0);
    gload16(gb1 + k0, d + lo1);
  };
  auto stageA = [&](int T, int buf) {
    int k0 = T * BK;
    bf16* d = la + (buf << 12);
    gload16(ga0 + k0, d + lo0);
    gload16(ga1 + k0, d + lo1);
  };
  auto loadA = [&](int T, float4* f) {
    const float* fp = gaf + (long)T * BK;
#pragma unroll
    for (int u = 0; u < 4; u++) f[u] = *(const float4*)(fp + 4 * u);
  };
  auto cvtwrite = [&](const float4* f, int buf) {
    alignas(16) bf16 tt[16];
#pragma unroll
    for (int u = 0; u < 4; u++) {
      tt[4 * u] = (bf16)f[u].x; tt[4 * u + 1] = (bf16)f[u].y;
      tt[4 * u + 2] = (bf16)f[u].z; tt[4 * u + 3] = (bf16)f[u].w;
    }
    bf16* d = la + (buf << 12) + lawo;
    *(uint4*)d = *(uint4*)tt;
    *(uint4*)(d + 8) = *(uint4*)(tt + 8);
  };
  auto compute = [&](int buf) {
    const bf16* pa = la + (buf << 12) + ((wr << 6) + l16) * BK + (quad << 3);
    const bf16* pb = lb + (buf << 12) + ((wc << 6) + l16) * BK + (quad << 3);
    bf16x8 afr[4], bfr[4];
#pragma unroll
    for (int i = 0; i < 4; i++) afr[i] = *(const bf16x8*)(pa + (i << 4) * BK);
#pragma unroll
    for (int j = 0; j < 4; j++) bfr[j] = *(const bf16x8*)(pb + (j << 4) * BK);
#pragma unroll
    for (int i = 0; i < 4; i++)
#pragma unroll
      for (int j = 0; j < 4; j++)
        acc[i][j] = __builtin_amdgcn_mfma_f32_16x16x32_bf16(afr[i], bfr[j], acc[i][j], 0, 0, 0);
  };

  if (!af32) {
    // ---- bf16 path: stage(t) retired one full phase after issue; never vmcnt(0) ----
    stageB(0, 0); stageA(0, 0);
    asm volatile("s_waitcnt vmcnt(0)" ::: "memory");
    bar();
    for (int t = 0; t < nk - 1; ++t) {
      stageB(t + 1, (t + 1) & 1);
      stageA(t + 1, (t + 1) & 1);
      asm volatile("s_waitcnt vmcnt(4)" ::: "memory");  // retire stage(t); t+1 in flight
      bar();                                            // stage(t) visible to all waves
      compute(t & 1);
      bar();                                            // reads of buf t&1 done pre-restage
    }
    asm volatile("s_waitcnt vmcnt(0)" ::: "memory");    // retire stage(nk-1)
    bar();
    compute((nk - 1) & 1);
  } else {
    // ---- fp32-A path: B via DMA (1-phase cover), A floats 2 phases ahead ----
    stageB(0, 0);
    { float4 f0[4]; loadA(0, f0); cvtwrite(f0, 0); }  // implicit wait also retires B(0)
    float4 fP[4];
    loadA(1, fP);                                     // F(1) in flight (nk >= 2 always)
    asm volatile("s_waitcnt lgkmcnt(0)" ::: "memory");
    bar();
    for (int t = 0; t < nk - 1; ++t) {
      stageB(t + 1, (t + 1) & 1);          // 2 ops
      float4 fN[4];
      bool hasF = (t + 2 < nk);
      if (hasF) loadA(t + 2, fN);          // 4 ops
      // steady queue: B(t)2,F(t+1)4,B(t+1)2,F(t+2)4 = 12 -> retire B(t)+F(t+1)
      asm volatile("s_waitcnt vmcnt(6)" ::: "memory");
      bar();                               // B(t) visible; A(t) visible via prev lgkm+bar
      compute(t & 1);
      cvtwrite(fP, (t + 1) & 1);           // F(t+1) already retired (edge: compiler waits)
      if (hasF) { fP[0] = fN[0]; fP[1] = fN[1]; fP[2] = fN[2]; fP[3] = fN[3]; }
      asm volatile("s_waitcnt lgkmcnt(0)" ::: "memory");  // my ds_writes complete
      bar();                               // readers of buf t&1 done before restage
    }
    asm volatile("s_waitcnt vmcnt(0)" ::: "memory");  // retire B(nk-1)
    bar();
    compute((nk - 1) & 1);
  }

  // C/D layout: col = lane&15, row = quad*4 + reg
  if (vt_out && n0 >= vcol0) {
    // V region of gemm1: write V^T[b][hd][s] directly (packed 8B stores)
#pragma unroll
    for (int i = 0; i < 4; i++)
#pragma unroll
      for (int j = 0; j < 4; j++) {
        int col = n0 + (wc << 6) + (j << 4) + l16;
        int hdg = col - vcol0;                            // 0..511 = kh*128+hd
        int row0 = m0 + (wr << 6) + (i << 4) + (quad << 2);
        int bb = row0 >> 11, s = row0 & 2047;             // row0 % 4 == 0: no b crossing
        ushort4 p;
        p.x = bfb(acc[i][j][0]); p.y = bfb(acc[i][j][1]);
        p.z = bfb(acc[i][j][2]); p.w = bfb(acc[i][j][3]);
        *(ushort4*)(vt_out + (((long)(bb * 512 + hdg)) << 11) + s) = p;
      }
  } else {
#pragma unroll
    for (int i = 0; i < 4; i++)
#pragma unroll
      for (int j = 0; j < 4; j++) {
        int col = n0 + (wc << 6) + (j << 4) + l16;
        if (col >= ncmax) continue;
#pragma unroll
        for (int r = 0; r < 4; r++) {
          long row = m0 + (wr << 6) + (i << 4) + (quad << 2) + r;
          float v = acc[i][j][r];
          if (cf32) ((float*)C)[row * ldc + col] = v;
          else      ((bf16*)C)[row * ldc + col] = (bf16)v;
        }
      }
  }
}

// ---------------- RoPE + scatter (Q pre-scaled by 1/sqrt(d)) ----------------
__global__ __launch_bounds__(256) void rope_scatter(
    const bf16* __restrict__ qkv, bf16* __restrict__ Q, bf16* __restrict__ Ko) {
  int row = blockIdx.x;  // b*S + s
  int b = row >> 11, s = row & 2047;
  int tid = threadIdx.x;
  const bf16* src = qkv + (long)row * QKW;
#pragma unroll
  for (int it = 0; it < 4; ++it) {
    int p = tid + it * 256;
    int h = p >> 6, i = p & 63;
    float x1 = (float)src[h * 128 + 2 * i];
    float x2 = (float)src[h * 128 + 2 * i + 1];
    float theta = __expf(-0.14391156831212787f * (float)i);  // 10000^(-2i/128)
    float sn, cs;
    sincosf((float)s * theta, &sn, &cs);
    long qb = ((long)(b * H_ + h) * S_ + s) * HD_;
    Q[qb + i]      = (bf16)((x1 * cs - x2 * sn) * SCALE);
    Q[qb + 64 + i] = (bf16)((x1 * sn + x2 * cs) * SCALE);
  }
  {
    int kh = tid >> 6, i = tid & 63;
    float x1 = (float)src[2048 + kh * 128 + 2 * i];
    float x2 = (float)src[2048 + kh * 128 + 2 * i + 1];
    float theta = __expf(-0.14391156831212787f * (float)i);
    float sn, cs;
    sincosf((float)s * theta, &sn, &cs);
    long kb = ((long)(b * HKV_ + kh) * S_ + s) * HD_;
    Ko[kb + i]      = (bf16)(x1 * cs - x2 * sn);
    Ko[kb + 64 + i] = (bf16)(x1 * sn + x2 * cs);
  }
}

// ---------------- flash attention ----------------
// S^T = K Q^T (lane l16 = qrow, regs = 4 keys) -> per-lane softmax -> PV straight from
// registers (S-accum == B-operand layout of v_mfma_f32_16x16x16bf16_1k). K/V staged by
// global_load_lds DMA (zero data VGPRs), double-buffered, XOR-swizzled per-lane SOURCE
// addressing so the lane-linear LDS image has conflict-free fragment reads.
// Causal load balance: block qt0 processes q-tiles {qt0, 31-qt0} -> every block does
// exactly 33 key-tiles; grid = 512 blocks = 2/CU (64KB LDS) -> one fully-resident,
// perfectly balanced pass. (DMA here is covered by ~48 MFMA + softmax per barrier.)
#define KTILE 8192  // 64 rows x 128 elems
#define VTILE 8192  // 128 rows x 64 elems

__global__ __launch_bounds__(256) void attn_kernel(
    const bf16* __restrict__ Q, const bf16* __restrict__ K,
    const bf16* __restrict__ Vt, bf16* __restrict__ O) {
  alignas(16) __shared__ bf16 Ks[2 * KTILE];  // 32 KB
  alignas(16) __shared__ bf16 Vs[2 * VTILE];  // 32 KB
  int qt0 = blockIdx.x;  // 0..15; paired with 31-qt0
  int h = blockIdx.y, b = blockIdx.z;
  int kh = h >> 2;
  int tid = threadIdx.x, wave = tid >> 6, lane = tid & 63;
  int quad = lane >> 4, l16 = lane & 15;
  const bf16* Kg = K + ((long)(b * HKV_ + kh) * S_) * HD_;
  const bf16* Vg = Vt + ((long)(b * HKV_ + kh) * HD_) * S_;

  // DMA source/dest offsets (elems). 16 calls/tile, call i = u*4+wave covers flat chunks
  // [i*64, i*64+64), chunk f: lane = f&63. K: r=f>>4, c=(f&15)^(r&15). V: v=f>>3, cv=(f&7)^(v&7).
  int kgo[4], vgo[4], klo[4], vlo[4];
#pragma unroll
  for (int u = 0; u < 4; u++) {
    int i = u * 4 + wave;
    int r = i * 4 + quad;                 // K row this lane fetches
    int c = l16 ^ (r & 15);               // swizzled chunk-in-row
    kgo[u] = r * HD_ + c * 8;
    klo[u] = i * 512;                     // wave-uniform LDS base (elems)
    int v = i * 8 + (lane >> 3);          // V^T row
    int cv = (lane & 7) ^ (v & 7);
    vgo[u] = v * S_ + cv * 8;
    vlo[u] = i * 512;
  }

  for (int hf = 0; hf < 2; ++hf) {
    int qt = hf ? 31 - qt0 : qt0;
    int q0 = qt * 64;
    const bf16* Qg = Q + ((long)(b * H_ + h) * S_ + q0) * HD_;

    // Q B-fragments in registers (pre-scaled by 1/sqrt(d)); lane l16 = qrow
    bf16x8 qb[4];
    {
      const bf16* qrow = Qg + (wave * 16 + l16) * HD_ + quad * 8;
#pragma unroll
      for (int kk = 0; kk < 4; kk++) qb[kk] = *(const bf16x8*)(qrow + kk * 32);
    }

    if (hf) __syncthreads();  // half-0 LDS readers done before re-preload of buf 0

    // preload tile 0 into buffer 0
#pragma unroll
    for (int u = 0; u < 4; u++) {
      gload16(Kg + kgo[u], Ks + klo[u]);
      gload16(Vg + vgo[u], Vs + vlo[u]);
    }

    f32x4 Of[8] = {};                   // O^T: col l16 = qrow, rows = hd
    float m_run = NEGINF, l_run = 0.f;  // per-lane state for qrow (wave*16 + l16)

    for (int kt = 0; kt <= qt; ++kt) {
      __syncthreads();  // drains DMA for buf (kt&1); prior readers of buf (kt&1)^1 done
      int p = kt & 1;
      if (kt < qt) {  // issue next-tile DMA into idle buffer; completes by next barrier
        const bf16* kn = Kg + (long)(kt + 1) * 8192;
        const bf16* vn = Vg + (long)(kt + 1) * 64;
        bf16* kd = Ks + (p ^ 1) * KTILE;
        bf16* vd = Vs + (p ^ 1) * VTILE;
#pragma unroll
        for (int u = 0; u < 4; u++) {
          gload16(kn + kgo[u], kd + klo[u]);
          gload16(vn + vgo[u], vd + vlo[u]);
        }
      }
      const bf16* kc = Ks + p * KTILE;
      const bf16* vc = Vs + p * VTILE;

      // S^T = K Q^T: A = K-frag (m = key), B = Q-frag (n = qrow)
      bool diag = (kt == qt);
      f32x4 sf[4];
      __builtin_amdgcn_s_setprio(1);  // T5: favor MFMA-issuing wave on the CU scheduler
#pragma unroll
      for (int jb = 0; jb < 4; jb++) {
        if (diag && jb > wave) {  // fully-masked key block on diagonal tile
          sf[jb] = (f32x4){NEGINF, NEGINF, NEGINF, NEGINF};
        } else {
          f32x4 a = {};
          const bf16* kbase = kc + (jb * 16 + l16) * 128;
#pragma unroll
          for (int kk = 0; kk < 4; kk++) {
            bf16x8 kf = *(const bf16x8*)(kbase + (((kk * 4 + quad) ^ l16) * 8));
            a = __builtin_amdgcn_mfma_f32_16x16x32_bf16(kf, qb[kk], a, 0, 0, 0);
          }
          sf[jb] = a;
        }
      }
      __builtin_amdgcn_s_setprio(0);
      if (diag) {  // partial mask on key block jb == wave (constant indices only)
#pragma unroll
        for (int jb = 0; jb < 4; jb++)
          if (jb == wave) {
#pragma unroll
            for (int r = 0; r < 4; r++)
              if (quad * 4 + r > l16) sf[jb][r] = NEGINF;
          }
      }

      // per-lane row max + 2 cross-quad shuffles
      float mx = NEGINF;
#pragma unroll
      for (int jb = 0; jb < 4; jb++)
#pragma unroll
        for (int r = 0; r < 4; r++) mx = fmaxf(mx, sf[jb][r]);
      mx = fmaxf(mx, __shfl_xor(mx, 16));
      mx = fmaxf(mx, __shfl_xor(mx, 32));
      // T13 defer-max: skip O-rescale while max grows <= 8 (P bounded by e^8, safe in
      // bf16/f32-accum; first tile always triggers since m_run = NEGINF)
      if (__any(mx > m_run + 8.0f)) {
        float mnew = fmaxf(m_run, mx);
        float alpha = __expf(m_run - mnew);
        m_run = mnew;
        l_run *= alpha;
#pragma unroll
        for (int n = 0; n < 8; n++) Of[n] *= alpha;
      }

      // p = exp(s - m): stays in registers as the PV B-operand
      float ls = 0.f;
      s16x4 pk[4];
#pragma unroll
      for (int jb = 0; jb < 4; jb++) {
        float p0 = __expf(sf[jb][0] - m_run);
        float p1 = __expf(sf[jb][1] - m_run);
        float p2 = __expf(sf[jb][2] - m_run);
        float p3 = __expf(sf[jb][3] - m_run);
        ls += (p0 + p1) + (p2 + p3);
        s16x4 t;
        t.x = (short)bfb(p0); t.y = (short)bfb(p1);
        t.z = (short)bfb(p2); t.w = (short)bfb(p3);
        pk[jb] = t;
      }
      l_run += ls;

      // O^T += V^T P^T via 16x16x16 MFMA (A = V^T frag from swizzled LDS, B = pk regs)
      __builtin_amdgcn_s_setprio(1);
#pragma unroll
      for (int jb = 0; jb < 4; jb++) {
        if (diag && jb > wave) continue;  // p == 0
#pragma unroll
        for (int n = 0; n < 8; n++) {
          int v = n * 16 + l16;
          const bf16* va_p = vc + v * 64 + (((jb * 2 + (quad >> 1)) ^ (l16 & 7)) * 8) + (quad & 1) * 4;
          s16x4 va = *(const s16x4*)va_p;
          Of[n] = __builtin_amdgcn_mfma_f32_16x16x16bf16_1k(va, pk[jb], Of[n], 0, 0, 0);
        }
      }
      __builtin_amdgcn_s_setprio(0);
    }

    // epilogue: reduce l across quads, packed 8B stores
    l_run += __shfl_xor(l_run, 16);
    l_run += __shfl_xor(l_run, 32);
    float inv = 1.0f / fmaxf(l_run, 1e-30f);
    bf16* Ob = O + ((long)(b * S_) + q0 + wave * 16 + l16) * D_ + h * HD_;
#pragma unroll
    for (int n = 0; n < 8; n++) {
      ushort4 w;
      w.x = bfb(Of[n][0] * inv); w.y = bfb(Of[n][1] * inv);
      w.z = bfb(Of[n][2] * inv); w.w = bfb(Of[n][3] * inv);
      *(ushort4*)(Ob + n * 16 + quad * 4) = w;
    }
  }
}

// ---------------- launch ----------------
extern "C" void kernel_launch(void* const* d_in, const int* in_sizes, int n_in,
                              void* d_out, int out_size, void* d_ws, size_t ws_size,
                              hipStream_t stream) {
  const void* x  = d_in[0];
  const void* Wq = d_in[1];
  const void* Wk = d_in[2];
  const void* Wv = d_in[3];
  const void* Wo = d_in[4];
  bf16* ws = (bf16*)d_ws;
  int* flag = (int*)d_ws;

  // workspace (bf16 elem offsets), peak 23,068,688 elems = 46.1 MB (proven)
  bf16* qkv   = ws + 16;        // 4096 x 2560          gemm1 -> rope
  bf16* Vtb   = ws + 10485776;  // 2 x 512 x 2048       gemm1 epilogue -> attn
  bf16* Qb    = ws + 12582928;  // 2x16x2048x128        rope -> attn
  bf16* wqkvT = ws + 12582928;  // 3072x2048 (overlaps Qb; dead before rope writes)
  bf16* Kb    = ws + 20971536;  // 2x4x2048x128         rope -> attn
  bf16* attno = ws + 16;        // reuse qkv            attn -> gemm2
  bf16* woT   = ws + 10485776;  // reuse Vtb/Qb region  (transposed after attn)

  dim3 tb(32, 8);
  detect_dtype<<<1, 256, 0, stream>>>((const unsigned*)x, flag);
  transpose_qkvw<<<dim3(64, 64, 3), tb, 0, stream>>>(Wq, Wk, Wv, wqkvT, flag);
  // qkv = x @ [Wq|Wk|Wv]; q,k cols -> qkv (ldc 2560), v cols -> Vtb transposed
  gemm_bt<<<dim3(QKVW / BN, (B_ * S_) / BM), 256, 0, stream>>>(
      x, wqkvT, qkv, B_ * S_, QKVW, D_, QKW, QKW, Vtb, QKW, flag, 1, 0);
  rope_scatter<<<B_ * S_, 256, 0, stream>>>(qkv, Qb, Kb);
  // paired-causal grid: 16 x 16 x 2 = 512 blocks, each does q-tiles {qt0, 31-qt0}
  attn_kernel<<<dim3(S_ / 128, H_, B_), 256, 0, stream>>>(Qb, Kb, Vtb, attno);
  transpose_cvt<<<dim3(64, 64, 1), tb, 0, stream>>>(Wo, woT, 2048, 2048, flag);
  // out = attno @ Wo (output dtype per flag)
  gemm_bt<<<dim3(D_ / BN, (B_ * S_) / BM), 256, 0, stream>>>(
      attno, woT, d_out, B_ * S_, D_, D_, D_, D_, nullptr, 0, flag, 0, 1);
}

// Round 7
// 386.635 us; speedup vs baseline: 1.1382x; 1.0310x over previous
//
#include <hip/hip_runtime.h>

typedef __bf16 bf16;
typedef __bf16 bf16x8 __attribute__((ext_vector_type(8)));
typedef float f32x4 __attribute__((ext_vector_type(4)));
typedef short s16x4 __attribute__((ext_vector_type(4)));

#define B_ 2
#define S_ 2048
#define D_ 2048
#define H_ 16
#define HKV_ 4
#define HD_ 128
#define QKVW 3072
#define QKW 2560                    // q+k columns (V handled separately)
#define SCALE 0.08838834764831845f  // 1/sqrt(128)
#define NEGINF -30000.0f            // finite -inf: exp underflows to 0, no inf-inf

// async global->LDS DMA, 16B per lane; LDS dest = wave-uniform base + lane*16
__device__ inline void gload16(const void* g, void* l) {
  __builtin_amdgcn_global_load_lds((const __attribute__((address_space(1))) unsigned int*)g,
                                   (__attribute__((address_space(3))) unsigned int*)l, 16, 0, 0);
}

__device__ inline unsigned short bfb(float v) {
  union { bf16 h; unsigned short u; } c;
  c.h = (bf16)v;
  return c.u;
}

// ---------------- dtype detection: bf16 or fp32 inputs? ----------------
__global__ void detect_dtype(const unsigned* __restrict__ xw, int* __restrict__ flag) {
  __shared__ int cnt;
  if (threadIdx.x == 0) cnt = 0;
  __syncthreads();
  unsigned w = xw[(size_t)threadIdx.x * 16384];
  unsigned low = w & 0xFFFFu;
  int e = (int)((low >> 7) & 0xFF);
  int vote = (low == 0u || (e >= 100 && e <= 140)) ? 1 : 0;
  atomicAdd(&cnt, vote);
  __syncthreads();
  if (threadIdx.x == 0) *flag = (cnt >= 128) ? 1 : 0;  // 1 = bf16, 0 = fp32
}

// ---------------- fused Wq/Wk/Wv transpose -> wqkvT (B^T layout) ----------------
__global__ __launch_bounds__(256) void transpose_qkvw(
    const void* __restrict__ Wq, const void* __restrict__ Wk, const void* __restrict__ Wv,
    bf16* __restrict__ wqkvT, const int* __restrict__ flag) {
  int z = blockIdx.z;
  const void* in = (z == 0) ? Wq : (z == 1) ? Wk : Wv;
  int cols = (z == 0) ? 2048 : 512;
  bf16* out = wqkvT + ((z == 0) ? 0 : (z == 1) ? 2048 * 2048 : 2560 * 2048);
  if (blockIdx.x * 32 >= cols) return;
  int fm = *flag;
  __shared__ float tile[32][33];
  int c0 = blockIdx.x * 32, r0 = blockIdx.y * 32;
  int tx = threadIdx.x, ty = threadIdx.y;  // 32 x 8
#pragma unroll
  for (int i = 0; i < 32; i += 8) {
    long idx = (long)(r0 + ty + i) * cols + c0 + tx;
    tile[ty + i][tx] = fm ? (float)((const bf16*)in)[idx] : ((const float*)in)[idx];
  }
  __syncthreads();
#pragma unroll
  for (int i = 0; i < 32; i += 8)
    out[(long)(c0 + ty + i) * 2048 + r0 + tx] = (bf16)tile[tx][ty + i];
}

// ---------------- generic transpose (+dtype-adaptive read) for Wo ----------------
__global__ __launch_bounds__(256) void transpose_cvt(
    const void* __restrict__ in, bf16* __restrict__ out,
    long in_stride, long out_stride, const int* __restrict__ flag) {
  __shared__ float tile[32][33];
  int fm = *flag;
  int c0 = blockIdx.x * 32, r0 = blockIdx.y * 32;
  int tx = threadIdx.x, ty = threadIdx.y;
#pragma unroll
  for (int i = 0; i < 32; i += 8) {
    long idx = (long)(r0 + ty + i) * in_stride + c0 + tx;
    tile[ty + i][tx] = fm ? (float)((const bf16*)in)[idx] : ((const float*)in)[idx];
  }
  __syncthreads();
#pragma unroll
  for (int i = 0; i < 32; i += 8)
    out[(long)(c0 + ty + i) * out_stride + r0 + tx] = (bf16)tile[tx][ty + i];
}

// ---------------- GEMM: C = A * Bt^T ----------------
// EXACT R3 structure (best measured: 2-phase dbuf, BK=32, 32 KB LDS, one
// __syncthreads per K-step, T14 split for fp32-A, T1 XCD swizzle) + ONE change:
// mod-4 rotation swizzle of the 16B chunks within each 32-elem LDS row,
//   slot(row, c) = (c + (row >> 1)) & 3
// Why: fragment ds_reads are 16B/lane at 64B row stride; bank-granule group =
// 4*(row&1) + slot. Rotation makes rows 0..7 of each 16-row fragment hit all 8
// granule-groups exactly once (2 lanes/granule = free, m136) instead of 4 groups
// twice; the af32 cvtwrite becomes uniform too (was clustered on even groups).
// Applied BOTH sides (rule #21): DMA *source* chunk carries the inverse rotation
// (LDS dest stays lane-linear as global_load_lds requires); reads apply the
// forward rotation. LDS size / occupancy / DMA count / barriers: identical to R3.
#define BM 128
#define BN 128
#define BK 32

__global__ __launch_bounds__(256) void gemm_bt(
    const void* __restrict__ A, const bf16* __restrict__ Bt, void* __restrict__ C,
    int M, int N, int K, int ldc, int ncmax,
    bf16* __restrict__ vt_out, int vcol0,
    const int* __restrict__ flag, int adyn, int cdyn) {
  alignas(16) __shared__ bf16 la[2 * BM * BK];  // 2 x 8 KB, unpadded (DMA lane-linear)
  alignas(16) __shared__ bf16 lb[2 * BN * BK];  // 2 x 8 KB
  int fm = flag ? *flag : 1;
  bool af32 = adyn && !fm;
  bool cf32 = cdyn && !fm;
  int tid = threadIdx.x;
  int wave = tid >> 6, lane = tid & 63;
  int wr = wave >> 1, wc = wave & 1;
  int quad = lane >> 4, l16 = lane & 15;

  // T1: XCD-aware block swizzle (nwg % 8 == 0 for both launches)
  int nwg = (int)(gridDim.x * gridDim.y);
  int flat = (int)(blockIdx.y * gridDim.x + blockIdx.x);
  int cpx = nwg >> 3;
  int wk = (flat & 7) * cpx + (flat >> 3);
  int bx = wk % (int)gridDim.x, by = wk / (int)gridDim.x;
  int m0 = by * BM, n0 = bx * BN;

  f32x4 acc[4][4] = {};

  // DMA coords: lane covers row sr = wave*16 + lane/4, LDS slot chunk lane&3.
  // Rotation: slot = (c_global + (row>>1)) & 3  =>  source chunk = (slot - sr>>1) & 3.
  int sr = (wave << 4) + (lane >> 2);
  int sc = (((lane & 3) - (sr >> 1)) & 3) << 3;  // rotated source chunk (elems)
  const bf16* gb0 = Bt + (long)(n0 + sr) * K + sc;
  const bf16* gb1 = Bt + (long)(n0 + 64 + sr) * K + sc;  // row+64: (64>>1)&3==0, same sc
  int lo0 = (wave << 9);          // wave-uniform LDS staging offsets (elems)
  int lo1 = 2048 + (wave << 9);
  const bf16* ga0 = nullptr; const bf16* ga1 = nullptr;
  const float* gaf = nullptr;
  int fr = tid >> 1, fh = (tid & 1) << 4;  // fp32-A path: row, 16-elem half
  if (af32) gaf = (const float*)A + (long)(m0 + fr) * K + fh;
  else { ga0 = (const bf16*)A + (long)(m0 + sr) * K + sc;
         ga1 = (const bf16*)A + (long)(m0 + 64 + sr) * K + sc; }
  // af32 rotated write slots: chunks c0, c0+1 of row fr
  int c0 = fh >> 3;                    // 0 or 2
  int k2 = (fr >> 1) & 3;
  int ws0 = ((c0 + k2) & 3) << 3;      // slot byte offsets (elems)
  int ws1 = ((c0 + 1 + k2) & 3) << 3;

  int nk = K / BK;

  auto cvtwrite = [&](const float4* f, int buf) {
    alignas(16) bf16 tt[16];
#pragma unroll
    for (int u = 0; u < 4; u++) {
      tt[4 * u] = (bf16)f[u].x; tt[4 * u + 1] = (bf16)f[u].y;
      tt[4 * u + 2] = (bf16)f[u].z; tt[4 * u + 3] = (bf16)f[u].w;
    }
    bf16* rowp = la + (buf << 12) + fr * BK;
    *(uint4*)(rowp + ws0) = *(uint4*)tt;
    *(uint4*)(rowp + ws1) = *(uint4*)(tt + 8);
  };
  auto compute = [&](int buf) {
    const bf16* baA = la + (buf << 12);
    const bf16* baB = lb + (buf << 12);
    bf16x8 afr[4], bfr[4];
#pragma unroll
    for (int i = 0; i < 4; i++) {
      int rowA = (wr << 6) + (i << 4) + l16;
      afr[i] = *(const bf16x8*)(baA + rowA * BK + (((quad + (rowA >> 1)) & 3) << 3));
    }
#pragma unroll
    for (int j = 0; j < 4; j++) {
      int rowB = (wc << 6) + (j << 4) + l16;
      bfr[j] = *(const bf16x8*)(baB + rowB * BK + (((quad + (rowB >> 1)) & 3) << 3));
    }
#pragma unroll
    for (int i = 0; i < 4; i++)
#pragma unroll
      for (int j = 0; j < 4; j++)
        acc[i][j] = __builtin_amdgcn_mfma_f32_16x16x32_bf16(afr[i], bfr[j], acc[i][j], 0, 0, 0);
  };

  // ---- prologue: stage tile 0 into buffer 0 (full drain once) ----
  gload16(gb0, lb + lo0);
  gload16(gb1, lb + lo1);
  if (af32) {
    float4 f0[4];
#pragma unroll
    for (int u = 0; u < 4; u++) f0[u] = *(const float4*)(gaf + 4 * u);
    cvtwrite(f0, 0);
  } else {
    gload16(ga0, la + lo0);
    gload16(ga1, la + lo1);
  }
  __syncthreads();

  // ---- main loop: ONE barrier per K-step; stage t+1 overlaps compute t ----
  for (int t = 0; t < nk; ++t) {
    int cur = t & 1, nxt = cur ^ 1;
    bool hasnext = (t + 1 < nk);
    float4 f[4];
    if (hasnext) {
      int k0 = (t + 1) * BK;
      gload16(gb0 + k0, lb + (nxt << 12) + lo0);
      gload16(gb1 + k0, lb + (nxt << 12) + lo1);
      if (af32) {
        const float* fp = gaf + k0;
#pragma unroll
        for (int u = 0; u < 4; u++) f[u] = *(const float4*)(fp + 4 * u);
      } else {
        gload16(ga0 + k0, la + (nxt << 12) + lo0);
        gload16(ga1 + k0, la + (nxt << 12) + lo1);
      }
    }

    compute(cur);

    if (hasnext && af32) cvtwrite(f, nxt);  // f32 loads landed during MFMA
    __syncthreads();  // drains DMA (next tile ready) + all readers of cur done
  }

  // C/D layout: col = lane&15, row = quad*4 + reg
  if (vt_out && n0 >= vcol0) {
    // V region of gemm1: write V^T[b][hd][s] directly (packed 8B stores)
#pragma unroll
    for (int i = 0; i < 4; i++)
#pragma unroll
      for (int j = 0; j < 4; j++) {
        int col = n0 + (wc << 6) + (j << 4) + l16;
        int hdg = col - vcol0;                            // 0..511 = kh*128+hd
        int row0 = m0 + (wr << 6) + (i << 4) + (quad << 2);
        int bb = row0 >> 11, s = row0 & 2047;             // row0 % 4 == 0: no b crossing
        ushort4 p;
        p.x = bfb(acc[i][j][0]); p.y = bfb(acc[i][j][1]);
        p.z = bfb(acc[i][j][2]); p.w = bfb(acc[i][j][3]);
        *(ushort4*)(vt_out + (((long)(bb * 512 + hdg)) << 11) + s) = p;
      }
  } else {
#pragma unroll
    for (int i = 0; i < 4; i++)
#pragma unroll
      for (int j = 0; j < 4; j++) {
        int col = n0 + (wc << 6) + (j << 4) + l16;
        if (col >= ncmax) continue;
#pragma unroll
        for (int r = 0; r < 4; r++) {
          long row = m0 + (wr << 6) + (i << 4) + (quad << 2) + r;
          float v = acc[i][j][r];
          if (cf32) ((float*)C)[row * ldc + col] = v;
          else      ((bf16*)C)[row * ldc + col] = (bf16)v;
        }
      }
  }
}

// ---------------- RoPE + scatter (Q pre-scaled by 1/sqrt(d)) ----------------
__global__ __launch_bounds__(256) void rope_scatter(
    const bf16* __restrict__ qkv, bf16* __restrict__ Q, bf16* __restrict__ Ko) {
  int row = blockIdx.x;  // b*S + s
  int b = row >> 11, s = row & 2047;
  int tid = threadIdx.x;
  const bf16* src = qkv + (long)row * QKW;
#pragma unroll
  for (int it = 0; it < 4; ++it) {
    int p = tid + it * 256;
    int h = p >> 6, i = p & 63;
    float x1 = (float)src[h * 128 + 2 * i];
    float x2 = (float)src[h * 128 + 2 * i + 1];
    float theta = __expf(-0.14391156831212787f * (float)i);  // 10000^(-2i/128)
    float sn, cs;
    sincosf((float)s * theta, &sn, &cs);
    long qb = ((long)(b * H_ + h) * S_ + s) * HD_;
    Q[qb + i]      = (bf16)((x1 * cs - x2 * sn) * SCALE);
    Q[qb + 64 + i] = (bf16)((x1 * sn + x2 * cs) * SCALE);
  }
  {
    int kh = tid >> 6, i = tid & 63;
    float x1 = (float)src[2048 + kh * 128 + 2 * i];
    float x2 = (float)src[2048 + kh * 128 + 2 * i + 1];
    float theta = __expf(-0.14391156831212787f * (float)i);
    float sn, cs;
    sincosf((float)s * theta, &sn, &cs);
    long kb = ((long)(b * HKV_ + kh) * S_ + s) * HD_;
    Ko[kb + i]      = (bf16)(x1 * cs - x2 * sn);
    Ko[kb + 64 + i] = (bf16)(x1 * sn + x2 * cs);
  }
}

// ---------------- flash attention ----------------
// S^T = K Q^T (lane l16 = qrow, regs = 4 keys) -> per-lane softmax -> PV straight from
// registers (S-accum == B-operand layout of v_mfma_f32_16x16x16bf16_1k). K/V staged by
// global_load_lds DMA (zero data VGPRs), double-buffered, XOR-swizzled per-lane SOURCE
// addressing so the lane-linear LDS image has conflict-free fragment reads.
// Causal load balance: block qt0 processes q-tiles {qt0, 31-qt0} -> every block does
// exactly 33 key-tiles; grid = 512 blocks = 2/CU (64KB LDS) -> one fully-resident,
// perfectly balanced pass. (DMA here is covered by ~48 MFMA + softmax per barrier.)
#define KTILE 8192  // 64 rows x 128 elems
#define VTILE 8192  // 128 rows x 64 elems

__global__ __launch_bounds__(256) void attn_kernel(
    const bf16* __restrict__ Q, const bf16* __restrict__ K,
    const bf16* __restrict__ Vt, bf16* __restrict__ O) {
  alignas(16) __shared__ bf16 Ks[2 * KTILE];  // 32 KB
  alignas(16) __shared__ bf16 Vs[2 * VTILE];  // 32 KB
  int qt0 = blockIdx.x;  // 0..15; paired with 31-qt0
  int h = blockIdx.y, b = blockIdx.z;
  int kh = h >> 2;
  int tid = threadIdx.x, wave = tid >> 6, lane = tid & 63;
  int quad = lane >> 4, l16 = lane & 15;
  const bf16* Kg = K + ((long)(b * HKV_ + kh) * S_) * HD_;
  const bf16* Vg = Vt + ((long)(b * HKV_ + kh) * HD_) * S_;

  // DMA source/dest offsets (elems). 16 calls/tile, call i = u*4+wave covers flat chunks
  // [i*64, i*64+64), chunk f: lane = f&63. K: r=f>>4, c=(f&15)^(r&15). V: v=f>>3, cv=(f&7)^(v&7).
  int kgo[4], vgo[4], klo[4], vlo[4];
#pragma unroll
  for (int u = 0; u < 4; u++) {
    int i = u * 4 + wave;
    int r = i * 4 + quad;                 // K row this lane fetches
    int c = l16 ^ (r & 15);               // swizzled chunk-in-row
    kgo[u] = r * HD_ + c * 8;
    klo[u] = i * 512;                     // wave-uniform LDS base (elems)
    int v = i * 8 + (lane >> 3);          // V^T row
    int cv = (lane & 7) ^ (v & 7);
    vgo[u] = v * S_ + cv * 8;
    vlo[u] = i * 512;
  }

  for (int hf = 0; hf < 2; ++hf) {
    int qt = hf ? 31 - qt0 : qt0;
    int q0 = qt * 64;
    const bf16* Qg = Q + ((long)(b * H_ + h) * S_ + q0) * HD_;

    // Q B-fragments in registers (pre-scaled by 1/sqrt(d)); lane l16 = qrow
    bf16x8 qb[4];
    {
      const bf16* qrow = Qg + (wave * 16 + l16) * HD_ + quad * 8;
#pragma unroll
      for (int kk = 0; kk < 4; kk++) qb[kk] = *(const bf16x8*)(qrow + kk * 32);
    }

    if (hf) __syncthreads();  // half-0 LDS readers done before re-preload of buf 0

    // preload tile 0 into buffer 0
#pragma unroll
    for (int u = 0; u < 4; u++) {
      gload16(Kg + kgo[u], Ks + klo[u]);
      gload16(Vg + vgo[u], Vs + vlo[u]);
    }

    f32x4 Of[8] = {};                   // O^T: col l16 = qrow, rows = hd
    float m_run = NEGINF, l_run = 0.f;  // per-lane state for qrow (wave*16 + l16)

    for (int kt = 0; kt <= qt; ++kt) {
      __syncthreads();  // drains DMA for buf (kt&1); prior readers of buf (kt&1)^1 done
      int p = kt & 1;
      if (kt < qt) {  // issue next-tile DMA into idle buffer; completes by next barrier
        const bf16* kn = Kg + (long)(kt + 1) * 8192;
        const bf16* vn = Vg + (long)(kt + 1) * 64;
        bf16* kd = Ks + (p ^ 1) * KTILE;
        bf16* vd = Vs + (p ^ 1) * VTILE;
#pragma unroll
        for (int u = 0; u < 4; u++) {
          gload16(kn + kgo[u], kd + klo[u]);
          gload16(vn + vgo[u], vd + vlo[u]);
        }
      }
      const bf16* kc = Ks + p * KTILE;
      const bf16* vc = Vs + p * VTILE;

      // S^T = K Q^T: A = K-frag (m = key), B = Q-frag (n = qrow)
      bool diag = (kt == qt);
      f32x4 sf[4];
      __builtin_amdgcn_s_setprio(1);  // T5: favor MFMA-issuing wave on the CU scheduler
#pragma unroll
      for (int jb = 0; jb < 4; jb++) {
        if (diag && jb > wave) {  // fully-masked key block on diagonal tile
          sf[jb] = (f32x4){NEGINF, NEGINF, NEGINF, NEGINF};
        } else {
          f32x4 a = {};
          const bf16* kbase = kc + (jb * 16 + l16) * 128;
#pragma unroll
          for (int kk = 0; kk < 4; kk++) {
            bf16x8 kf = *(const bf16x8*)(kbase + (((kk * 4 + quad) ^ l16) * 8));
            a = __builtin_amdgcn_mfma_f32_16x16x32_bf16(kf, qb[kk], a, 0, 0, 0);
          }
          sf[jb] = a;
        }
      }
      __builtin_amdgcn_s_setprio(0);
      if (diag) {  // partial mask on key block jb == wave (constant indices only)
#pragma unroll
        for (int jb = 0; jb < 4; jb++)
          if (jb == wave) {
#pragma unroll
            for (int r = 0; r < 4; r++)
              if (quad * 4 + r > l16) sf[jb][r] = NEGINF;
          }
      }

      // per-lane row max + 2 cross-quad shuffles
      float mx = NEGINF;
#pragma unroll
      for (int jb = 0; jb < 4; jb++)
#pragma unroll
        for (int r = 0; r < 4; r++) mx = fmaxf(mx, sf[jb][r]);
      mx = fmaxf(mx, __shfl_xor(mx, 16));
      mx = fmaxf(mx, __shfl_xor(mx, 32));
      // T13 defer-max: skip O-rescale while max grows <= 8 (P bounded by e^8, safe in
      // bf16/f32-accum; first tile always triggers since m_run = NEGINF)
      if (__any(mx > m_run + 8.0f)) {
        float mnew = fmaxf(m_run, mx);
        float alpha = __expf(m_run - mnew);
        m_run = mnew;
        l_run *= alpha;
#pragma unroll
        for (int n = 0; n < 8; n++) Of[n] *= alpha;
      }

      // p = exp(s - m): stays in registers as the PV B-operand
      float ls = 0.f;
      s16x4 pk[4];
#pragma unroll
      for (int jb = 0; jb < 4; jb++) {
        float p0 = __expf(sf[jb][0] - m_run);
        float p1 = __expf(sf[jb][1] - m_run);
        float p2 = __expf(sf[jb][2] - m_run);
        float p3 = __expf(sf[jb][3] - m_run);
        ls += (p0 + p1) + (p2 + p3);
        s16x4 t;
        t.x = (short)bfb(p0); t.y = (short)bfb(p1);
        t.z = (short)bfb(p2); t.w = (short)bfb(p3);
        pk[jb] = t;
      }
      l_run += ls;

      // O^T += V^T P^T via 16x16x16 MFMA (A = V^T frag from swizzled LDS, B = pk regs)
      __builtin_amdgcn_s_setprio(1);
#pragma unroll
      for (int jb = 0; jb < 4; jb++) {
        if (diag && jb > wave) continue;  // p == 0
#pragma unroll
        for (int n = 0; n < 8; n++) {
          int v = n * 16 + l16;
          const bf16* va_p = vc + v * 64 + (((jb * 2 + (quad >> 1)) ^ (l16 & 7)) * 8) + (quad & 1) * 4;
          s16x4 va = *(const s16x4*)va_p;
          Of[n] = __builtin_amdgcn_mfma_f32_16x16x16bf16_1k(va, pk[jb], Of[n], 0, 0, 0);
        }
      }
      __builtin_amdgcn_s_setprio(0);
    }

    // epilogue: reduce l across quads, packed 8B stores
    l_run += __shfl_xor(l_run, 16);
    l_run += __shfl_xor(l_run, 32);
    float inv = 1.0f / fmaxf(l_run, 1e-30f);
    bf16* Ob = O + ((long)(b * S_) + q0 + wave * 16 + l16) * D_ + h * HD_;
#pragma unroll
    for (int n = 0; n < 8; n++) {
      ushort4 w;
      w.x = bfb(Of[n][0] * inv); w.y = bfb(Of[n][1] * inv);
      w.z = bfb(Of[n][2] * inv); w.w = bfb(Of[n][3] * inv);
      *(ushort4*)(Ob + n * 16 + quad * 4) = w;
    }
  }
}

// ---------------- launch ----------------
extern "C" void kernel_launch(void* const* d_in, const int* in_sizes, int n_in,
                              void* d_out, int out_size, void* d_ws, size_t ws_size,
                              hipStream_t stream) {
  const void* x  = d_in[0];
  const void* Wq = d_in[1];
  const void* Wk = d_in[2];
  const void* Wv = d_in[3];
  const void* Wo = d_in[4];
  bf16* ws = (bf16*)d_ws;
  int* flag = (int*)d_ws;

  // workspace (bf16 elem offsets), peak 23,068,688 elems = 46.1 MB (proven)
  bf16* qkv   = ws + 16;        // 4096 x 2560          gemm1 -> rope
  bf16* Vtb   = ws + 10485776;  // 2 x 512 x 2048       gemm1 epilogue -> attn
  bf16* Qb    = ws + 12582928;  // 2x16x2048x128        rope -> attn
  bf16* wqkvT = ws + 12582928;  // 3072x2048 (overlaps Qb; dead before rope writes)
  bf16* Kb    = ws + 20971536;  // 2x4x2048x128         rope -> attn
  bf16* attno = ws + 16;        // reuse qkv            attn -> gemm2
  bf16* woT   = ws + 10485776;  // reuse Vtb/Qb region  (transposed after attn)

  dim3 tb(32, 8);
  detect_dtype<<<1, 256, 0, stream>>>((const unsigned*)x, flag);
  transpose_qkvw<<<dim3(64, 64, 3), tb, 0, stream>>>(Wq, Wk, Wv, wqkvT, flag);
  // qkv = x @ [Wq|Wk|Wv]; q,k cols -> qkv (ldc 2560), v cols -> Vtb transposed
  gemm_bt<<<dim3(QKVW / BN, (B_ * S_) / BM), 256, 0, stream>>>(
      x, wqkvT, qkv, B_ * S_, QKVW, D_, QKW, QKW, Vtb, QKW, flag, 1, 0);
  rope_scatter<<<B_ * S_, 256, 0, stream>>>(qkv, Qb, Kb);
  // paired-causal grid: 16 x 16 x 2 = 512 blocks, each does q-tiles {qt0, 31-qt0}
  attn_kernel<<<dim3(S_ / 128, H_, B_), 256, 0, stream>>>(Qb, Kb, Vtb, attno);
  transpose_cvt<<<dim3(64, 64, 1), tb, 0, stream>>>(Wo, woT, 2048, 2048, flag);
  // out = attno @ Wo (output dtype per flag)
  gemm_bt<<<dim3(D_ / BN, (B_ * S_) / BM), 256, 0, stream>>>(
      attno, woT, d_out, B_ * S_, D_, D_, D_, D_, nullptr, 0, flag, 0, 1);
}

// Round 8
// 382.978 us; speedup vs baseline: 1.1491x; 1.0095x over previous
//
#include <hip/hip_runtime.h>

typedef __bf16 bf16;
typedef __bf16 bf16x8 __attribute__((ext_vector_type(8)));
typedef float f32x4 __attribute__((ext_vector_type(4)));
typedef short s16x4 __attribute__((ext_vector_type(4)));

#define B_ 2
#define S_ 2048
#define D_ 2048
#define H_ 16
#define HKV_ 4
#define HD_ 128
#define QKVW 3072
#define QKW 2560                    // q+k columns (V handled separately)
#define SCALE 0.08838834764831845f  // 1/sqrt(128)
#define NEGINF -30000.0f            // finite -inf: exp underflows to 0, no inf-inf

// async global->LDS DMA, 16B per lane; LDS dest = wave-uniform base + lane*16
__device__ inline void gload16(const void* g, void* l) {
  __builtin_amdgcn_global_load_lds((const __attribute__((address_space(1))) unsigned int*)g,
                                   (__attribute__((address_space(3))) unsigned int*)l, 16, 0, 0);
}

__device__ inline unsigned short bfb(float v) {
  union { bf16 h; unsigned short u; } c;
  c.h = (bf16)v;
  return c.u;
}

// ---------------- dtype detection: bf16 or fp32 inputs? ----------------
__global__ void detect_dtype(const unsigned* __restrict__ xw, int* __restrict__ flag) {
  __shared__ int cnt;
  if (threadIdx.x == 0) cnt = 0;
  __syncthreads();
  unsigned w = xw[(size_t)threadIdx.x * 16384];
  unsigned low = w & 0xFFFFu;
  int e = (int)((low >> 7) & 0xFF);
  int vote = (low == 0u || (e >= 100 && e <= 140)) ? 1 : 0;
  atomicAdd(&cnt, vote);
  __syncthreads();
  if (threadIdx.x == 0) *flag = (cnt >= 128) ? 1 : 0;  // 1 = bf16, 0 = fp32
}

// ---------------- fused Wq/Wk/Wv transpose -> wqkvT (B^T layout) ----------------
__global__ __launch_bounds__(256) void transpose_qkvw(
    const void* __restrict__ Wq, const void* __restrict__ Wk, const void* __restrict__ Wv,
    bf16* __restrict__ wqkvT, const int* __restrict__ flag) {
  int z = blockIdx.z;
  const void* in = (z == 0) ? Wq : (z == 1) ? Wk : Wv;
  int cols = (z == 0) ? 2048 : 512;
  bf16* out = wqkvT + ((z == 0) ? 0 : (z == 1) ? 2048 * 2048 : 2560 * 2048);
  if (blockIdx.x * 32 >= cols) return;
  int fm = *flag;
  __shared__ float tile[32][33];
  int c0 = blockIdx.x * 32, r0 = blockIdx.y * 32;
  int tx = threadIdx.x, ty = threadIdx.y;  // 32 x 8
#pragma unroll
  for (int i = 0; i < 32; i += 8) {
    long idx = (long)(r0 + ty + i) * cols + c0 + tx;
    tile[ty + i][tx] = fm ? (float)((const bf16*)in)[idx] : ((const float*)in)[idx];
  }
  __syncthreads();
#pragma unroll
  for (int i = 0; i < 32; i += 8)
    out[(long)(c0 + ty + i) * 2048 + r0 + tx] = (bf16)tile[tx][ty + i];
}

// ---------------- generic transpose (+dtype-adaptive read) for Wo ----------------
__global__ __launch_bounds__(256) void transpose_cvt(
    const void* __restrict__ in, bf16* __restrict__ out,
    long in_stride, long out_stride, const int* __restrict__ flag) {
  __shared__ float tile[32][33];
  int fm = *flag;
  int c0 = blockIdx.x * 32, r0 = blockIdx.y * 32;
  int tx = threadIdx.x, ty = threadIdx.y;
#pragma unroll
  for (int i = 0; i < 32; i += 8) {
    long idx = (long)(r0 + ty + i) * in_stride + c0 + tx;
    tile[ty + i][tx] = fm ? (float)((const bf16*)in)[idx] : ((const float*)in)[idx];
  }
  __syncthreads();
#pragma unroll
  for (int i = 0; i < 32; i += 8)
    out[(long)(c0 + ty + i) * out_stride + r0 + tx] = (bf16)tile[tx][ty + i];
}

// ---------------- GEMM: C = A * Bt^T ----------------
// R7 kernel unchanged (best measured, conflict-free): 2-phase dbuf, BK=32, 32 KB LDS,
// one __syncthreads per K-step, mod-4 rotation swizzle both-sides (bank conflicts = 0),
// T14 split for fp32-A, T1 XCD swizzle. R4-R7 established this structure's ceiling:
// cover/depth = null, occupancy loss = big regression, conflict-fix = free-but-null.
#define BM 128
#define BN 128
#define BK 32

__global__ __launch_bounds__(256) void gemm_bt(
    const void* __restrict__ A, const bf16* __restrict__ Bt, void* __restrict__ C,
    int M, int N, int K, int ldc, int ncmax,
    bf16* __restrict__ vt_out, int vcol0,
    const int* __restrict__ flag, int adyn, int cdyn) {
  alignas(16) __shared__ bf16 la[2 * BM * BK];  // 2 x 8 KB, unpadded (DMA lane-linear)
  alignas(16) __shared__ bf16 lb[2 * BN * BK];  // 2 x 8 KB
  int fm = flag ? *flag : 1;
  bool af32 = adyn && !fm;
  bool cf32 = cdyn && !fm;
  int tid = threadIdx.x;
  int wave = tid >> 6, lane = tid & 63;
  int wr = wave >> 1, wc = wave & 1;
  int quad = lane >> 4, l16 = lane & 15;

  // T1: XCD-aware block swizzle (nwg % 8 == 0 for both launches)
  int nwg = (int)(gridDim.x * gridDim.y);
  int flat = (int)(blockIdx.y * gridDim.x + blockIdx.x);
  int cpx = nwg >> 3;
  int wk = (flat & 7) * cpx + (flat >> 3);
  int bx = wk % (int)gridDim.x, by = wk / (int)gridDim.x;
  int m0 = by * BM, n0 = bx * BN;

  f32x4 acc[4][4] = {};

  // DMA coords: lane covers row sr = wave*16 + lane/4, LDS slot chunk lane&3.
  // Rotation: slot = (c_global + (row>>1)) & 3  =>  source chunk = (slot - sr>>1) & 3.
  int sr = (wave << 4) + (lane >> 2);
  int sc = (((lane & 3) - (sr >> 1)) & 3) << 3;  // rotated source chunk (elems)
  const bf16* gb0 = Bt + (long)(n0 + sr) * K + sc;
  const bf16* gb1 = Bt + (long)(n0 + 64 + sr) * K + sc;  // row+64: (64>>1)&3==0, same sc
  int lo0 = (wave << 9);          // wave-uniform LDS staging offsets (elems)
  int lo1 = 2048 + (wave << 9);
  const bf16* ga0 = nullptr; const bf16* ga1 = nullptr;
  const float* gaf = nullptr;
  int fr = tid >> 1, fh = (tid & 1) << 4;  // fp32-A path: row, 16-elem half
  if (af32) gaf = (const float*)A + (long)(m0 + fr) * K + fh;
  else { ga0 = (const bf16*)A + (long)(m0 + sr) * K + sc;
         ga1 = (const bf16*)A + (long)(m0 + 64 + sr) * K + sc; }
  // af32 rotated write slots: chunks c0, c0+1 of row fr
  int c0 = fh >> 3;                    // 0 or 2
  int k2 = (fr >> 1) & 3;
  int ws0 = ((c0 + k2) & 3) << 3;      // slot byte offsets (elems)
  int ws1 = ((c0 + 1 + k2) & 3) << 3;

  int nk = K / BK;

  auto cvtwrite = [&](const float4* f, int buf) {
    alignas(16) bf16 tt[16];
#pragma unroll
    for (int u = 0; u < 4; u++) {
      tt[4 * u] = (bf16)f[u].x; tt[4 * u + 1] = (bf16)f[u].y;
      tt[4 * u + 2] = (bf16)f[u].z; tt[4 * u + 3] = (bf16)f[u].w;
    }
    bf16* rowp = la + (buf << 12) + fr * BK;
    *(uint4*)(rowp + ws0) = *(uint4*)tt;
    *(uint4*)(rowp + ws1) = *(uint4*)(tt + 8);
  };
  auto compute = [&](int buf) {
    const bf16* baA = la + (buf << 12);
    const bf16* baB = lb + (buf << 12);
    bf16x8 afr[4], bfr[4];
#pragma unroll
    for (int i = 0; i < 4; i++) {
      int rowA = (wr << 6) + (i << 4) + l16;
      afr[i] = *(const bf16x8*)(baA + rowA * BK + (((quad + (rowA >> 1)) & 3) << 3));
    }
#pragma unroll
    for (int j = 0; j < 4; j++) {
      int rowB = (wc << 6) + (j << 4) + l16;
      bfr[j] = *(const bf16x8*)(baB + rowB * BK + (((quad + (rowB >> 1)) & 3) << 3));
    }
#pragma unroll
    for (int i = 0; i < 4; i++)
#pragma unroll
      for (int j = 0; j < 4; j++)
        acc[i][j] = __builtin_amdgcn_mfma_f32_16x16x32_bf16(afr[i], bfr[j], acc[i][j], 0, 0, 0);
  };

  // ---- prologue: stage tile 0 into buffer 0 (full drain once) ----
  gload16(gb0, lb + lo0);
  gload16(gb1, lb + lo1);
  if (af32) {
    float4 f0[4];
#pragma unroll
    for (int u = 0; u < 4; u++) f0[u] = *(const float4*)(gaf + 4 * u);
    cvtwrite(f0, 0);
  } else {
    gload16(ga0, la + lo0);
    gload16(ga1, la + lo1);
  }
  __syncthreads();

  // ---- main loop: ONE barrier per K-step; stage t+1 overlaps compute t ----
  for (int t = 0; t < nk; ++t) {
    int cur = t & 1, nxt = cur ^ 1;
    bool hasnext = (t + 1 < nk);
    float4 f[4];
    if (hasnext) {
      int k0 = (t + 1) * BK;
      gload16(gb0 + k0, lb + (nxt << 12) + lo0);
      gload16(gb1 + k0, lb + (nxt << 12) + lo1);
      if (af32) {
        const float* fp = gaf + k0;
#pragma unroll
        for (int u = 0; u < 4; u++) f[u] = *(const float4*)(fp + 4 * u);
      } else {
        gload16(ga0 + k0, la + (nxt << 12) + lo0);
        gload16(ga1 + k0, la + (nxt << 12) + lo1);
      }
    }

    compute(cur);

    if (hasnext && af32) cvtwrite(f, nxt);  // f32 loads landed during MFMA
    __syncthreads();  // drains DMA (next tile ready) + all readers of cur done
  }

  // C/D layout: col = lane&15, row = quad*4 + reg
  if (vt_out && n0 >= vcol0) {
    // V region of gemm1: write V^T[b][hd][s] directly (packed 8B stores)
#pragma unroll
    for (int i = 0; i < 4; i++)
#pragma unroll
      for (int j = 0; j < 4; j++) {
        int col = n0 + (wc << 6) + (j << 4) + l16;
        int hdg = col - vcol0;                            // 0..511 = kh*128+hd
        int row0 = m0 + (wr << 6) + (i << 4) + (quad << 2);
        int bb = row0 >> 11, s = row0 & 2047;             // row0 % 4 == 0: no b crossing
        ushort4 p;
        p.x = bfb(acc[i][j][0]); p.y = bfb(acc[i][j][1]);
        p.z = bfb(acc[i][j][2]); p.w = bfb(acc[i][j][3]);
        *(ushort4*)(vt_out + (((long)(bb * 512 + hdg)) << 11) + s) = p;
      }
  } else {
#pragma unroll
    for (int i = 0; i < 4; i++)
#pragma unroll
      for (int j = 0; j < 4; j++) {
        int col = n0 + (wc << 6) + (j << 4) + l16;
        if (col >= ncmax) continue;
#pragma unroll
        for (int r = 0; r < 4; r++) {
          long row = m0 + (wr << 6) + (i << 4) + (quad << 2) + r;
          float v = acc[i][j][r];
          if (cf32) ((float*)C)[row * ldc + col] = v;
          else      ((bf16*)C)[row * ldc + col] = (bf16)v;
        }
      }
  }
}

// ---------------- RoPE + scatter (Q pre-scaled by 1/sqrt(d)) ----------------
// All 5 segments share rotary index i = tid & 63 (256 = 0 mod 64), so theta and
// sincos are computed ONCE per thread (was 5x). Pair loads (x[2i], x[2i+1]) fetched
// as a single aligned uint; bf16 -> f32 is bits << 16.
__global__ __launch_bounds__(256) void rope_scatter(
    const bf16* __restrict__ qkv, bf16* __restrict__ Q, bf16* __restrict__ Ko) {
  int row = blockIdx.x;  // b*S + s
  int b = row >> 11, s = row & 2047;
  int tid = threadIdx.x;
  int i = tid & 63;
  const bf16* src = qkv + (long)row * QKW;
  float theta = __expf(-0.14391156831212787f * (float)i);  // 10000^(-2i/128)
  float sn, cs;
  sincosf((float)s * theta, &sn, &cs);
#pragma unroll
  for (int it = 0; it < 4; ++it) {
    int h = (tid + it * 256) >> 6;  // 0..15 over the 4 iterations
    unsigned v = *(const unsigned*)(src + h * 128 + 2 * i);
    float x1 = __uint_as_float(v << 16);
    float x2 = __uint_as_float(v & 0xFFFF0000u);
    long qb = ((long)(b * H_ + h) * S_ + s) * HD_;
    Q[qb + i]      = (bf16)((x1 * cs - x2 * sn) * SCALE);
    Q[qb + 64 + i] = (bf16)((x1 * sn + x2 * cs) * SCALE);
  }
  {
    int kh = tid >> 6;
    unsigned v = *(const unsigned*)(src + 2048 + kh * 128 + 2 * i);
    float x1 = __uint_as_float(v << 16);
    float x2 = __uint_as_float(v & 0xFFFF0000u);
    long kb = ((long)(b * HKV_ + kh) * S_ + s) * HD_;
    Ko[kb + i]      = (bf16)(x1 * cs - x2 * sn);
    Ko[kb + 64 + i] = (bf16)(x1 * sn + x2 * cs);
  }
}

// ---------------- flash attention ----------------
// S^T = K Q^T (lane l16 = qrow, regs = 4 keys) -> per-lane softmax -> PV straight from
// registers (S-accum == B-operand layout of v_mfma_f32_16x16x16bf16_1k). K/V staged by
// global_load_lds DMA (zero data VGPRs), double-buffered, XOR-swizzled per-lane SOURCE
// addressing so the lane-linear LDS image has conflict-free fragment reads.
// Causal load balance: block pairs q-tiles {qt0, 31-qt0} -> every block does exactly
// 33 key-tiles; 512 blocks = 2/CU, one fully-resident balanced pass.
// XCD partition: blockIdx%8 = b*4+kh (8 combos = 8 XCDs) -> each XCD's 64 blocks
// share ONE (b,kh) K/V working set (0.5+0.5 MB, fully L2-resident per XCD).
#define KTILE 8192  // 64 rows x 128 elems
#define VTILE 8192  // 128 rows x 64 elems

__global__ __launch_bounds__(256) void attn_kernel(
    const bf16* __restrict__ Q, const bf16* __restrict__ K,
    const bf16* __restrict__ Vt, bf16* __restrict__ O) {
  alignas(16) __shared__ bf16 Ks[2 * KTILE];  // 32 KB
  alignas(16) __shared__ bf16 Vs[2 * VTILE];  // 32 KB
  int bi = (int)blockIdx.x;        // 512 blocks, 1-D
  int cb = bi & 7;                 // XCD selector = (b, kh)
  int b = cb >> 2, kh = cb & 3;
  int r = bi >> 3;
  int qt0 = r >> 2;                // 0..15; paired with 31-qt0
  int h = kh * 4 + (r & 3);
  int tid = threadIdx.x, wave = tid >> 6, lane = tid & 63;
  int quad = lane >> 4, l16 = lane & 15;
  const bf16* Kg = K + ((long)(b * HKV_ + kh) * S_) * HD_;
  const bf16* Vg = Vt + ((long)(b * HKV_ + kh) * HD_) * S_;

  // DMA source/dest offsets (elems). 16 calls/tile, call i = u*4+wave covers flat chunks
  // [i*64, i*64+64), chunk f: lane = f&63. K: r=f>>4, c=(f&15)^(r&15). V: v=f>>3, cv=(f&7)^(v&7).
  int kgo[4], vgo[4], klo[4], vlo[4];
#pragma unroll
  for (int u = 0; u < 4; u++) {
    int i = u * 4 + wave;
    int rr = i * 4 + quad;                // K row this lane fetches
    int c = l16 ^ (rr & 15);              // swizzled chunk-in-row
    kgo[u] = rr * HD_ + c * 8;
    klo[u] = i * 512;                     // wave-uniform LDS base (elems)
    int v = i * 8 + (lane >> 3);          // V^T row
    int cv = (lane & 7) ^ (v & 7);
    vgo[u] = v * S_ + cv * 8;
    vlo[u] = i * 512;
  }

  for (int hf = 0; hf < 2; ++hf) {
    int qt = hf ? 31 - qt0 : qt0;
    int q0 = qt * 64;
    const bf16* Qg = Q + ((long)(b * H_ + h) * S_ + q0) * HD_;

    // Q B-fragments in registers (pre-scaled by 1/sqrt(d)); lane l16 = qrow
    bf16x8 qb[4];
    {
      const bf16* qrow = Qg + (wave * 16 + l16) * HD_ + quad * 8;
#pragma unroll
      for (int kk = 0; kk < 4; kk++) qb[kk] = *(const bf16x8*)(qrow + kk * 32);
    }

    if (hf) __syncthreads();  // half-0 LDS readers done before re-preload of buf 0

    // preload tile 0 into buffer 0
#pragma unroll
    for (int u = 0; u < 4; u++) {
      gload16(Kg + kgo[u], Ks + klo[u]);
      gload16(Vg + vgo[u], Vs + vlo[u]);
    }

    f32x4 Of[8] = {};                   // O^T: col l16 = qrow, rows = hd
    float m_run = NEGINF, l_run = 0.f;  // per-lane state for qrow (wave*16 + l16)

    for (int kt = 0; kt <= qt; ++kt) {
      __syncthreads();  // drains DMA for buf (kt&1); prior readers of buf (kt&1)^1 done
      int p = kt & 1;
      if (kt < qt) {  // issue next-tile DMA into idle buffer; completes by next barrier
        const bf16* kn = Kg + (long)(kt + 1) * 8192;
        const bf16* vn = Vg + (long)(kt + 1) * 64;
        bf16* kd = Ks + (p ^ 1) * KTILE;
        bf16* vd = Vs + (p ^ 1) * VTILE;
#pragma unroll
        for (int u = 0; u < 4; u++) {
          gload16(kn + kgo[u], kd + klo[u]);
          gload16(vn + vgo[u], vd + vlo[u]);
        }
      }
      const bf16* kc = Ks + p * KTILE;
      const bf16* vc = Vs + p * VTILE;

      // S^T = K Q^T: A = K-frag (m = key), B = Q-frag (n = qrow)
      bool diag = (kt == qt);
      f32x4 sf[4];
      __builtin_amdgcn_s_setprio(1);  // T5: favor MFMA-issuing wave on the CU scheduler
#pragma unroll
      for (int jb = 0; jb < 4; jb++) {
        if (diag && jb > wave) {  // fully-masked key block on diagonal tile
          sf[jb] = (f32x4){NEGINF, NEGINF, NEGINF, NEGINF};
        } else {
          f32x4 a = {};
          const bf16* kbase = kc + (jb * 16 + l16) * 128;
#pragma unroll
          for (int kk = 0; kk < 4; kk++) {
            bf16x8 kf = *(const bf16x8*)(kbase + (((kk * 4 + quad) ^ l16) * 8));
            a = __builtin_amdgcn_mfma_f32_16x16x32_bf16(kf, qb[kk], a, 0, 0, 0);
          }
          sf[jb] = a;
        }
      }
      __builtin_amdgcn_s_setprio(0);
      if (diag) {  // partial mask on key block jb == wave (constant indices only)
#pragma unroll
        for (int jb = 0; jb < 4; jb++)
          if (jb == wave) {
#pragma unroll
            for (int r2 = 0; r2 < 4; r2++)
              if (quad * 4 + r2 > l16) sf[jb][r2] = NEGINF;
          }
      }

      // per-lane row max + 2 cross-quad shuffles
      float mx = NEGINF;
#pragma unroll
      for (int jb = 0; jb < 4; jb++)
#pragma unroll
        for (int r2 = 0; r2 < 4; r2++) mx = fmaxf(mx, sf[jb][r2]);
      mx = fmaxf(mx, __shfl_xor(mx, 16));
      mx = fmaxf(mx, __shfl_xor(mx, 32));
      // T13 defer-max: skip O-rescale while max grows <= 8 (P bounded by e^8, safe in
      // bf16/f32-accum; first tile always triggers since m_run = NEGINF)
      if (__any(mx > m_run + 8.0f)) {
        float mnew = fmaxf(m_run, mx);
        float alpha = __expf(m_run - mnew);
        m_run = mnew;
        l_run *= alpha;
#pragma unroll
        for (int n = 0; n < 8; n++) Of[n] *= alpha;
      }

      // p = exp(s - m): stays in registers as the PV B-operand
      float ls = 0.f;
      s16x4 pk[4];
#pragma unroll
      for (int jb = 0; jb < 4; jb++) {
        float p0 = __expf(sf[jb][0] - m_run);
        float p1 = __expf(sf[jb][1] - m_run);
        float p2 = __expf(sf[jb][2] - m_run);
        float p3 = __expf(sf[jb][3] - m_run);
        ls += (p0 + p1) + (p2 + p3);
        s16x4 t;
        t.x = (short)bfb(p0); t.y = (short)bfb(p1);
        t.z = (short)bfb(p2); t.w = (short)bfb(p3);
        pk[jb] = t;
      }
      l_run += ls;

      // O^T += V^T P^T via 16x16x16 MFMA (A = V^T frag from swizzled LDS, B = pk regs)
      __builtin_amdgcn_s_setprio(1);
#pragma unroll
      for (int jb = 0; jb < 4; jb++) {
        if (diag && jb > wave) continue;  // p == 0
#pragma unroll
        for (int n = 0; n < 8; n++) {
          int v = n * 16 + l16;
          const bf16* va_p = vc + v * 64 + (((jb * 2 + (quad >> 1)) ^ (l16 & 7)) * 8) + (quad & 1) * 4;
          s16x4 va = *(const s16x4*)va_p;
          Of[n] = __builtin_amdgcn_mfma_f32_16x16x16bf16_1k(va, pk[jb], Of[n], 0, 0, 0);
        }
      }
      __builtin_amdgcn_s_setprio(0);
    }

    // epilogue: reduce l across quads, packed 8B stores
    l_run += __shfl_xor(l_run, 16);
    l_run += __shfl_xor(l_run, 32);
    float inv = 1.0f / fmaxf(l_run, 1e-30f);
    bf16* Ob = O + ((long)(b * S_) + q0 + wave * 16 + l16) * D_ + h * HD_;
#pragma unroll
    for (int n = 0; n < 8; n++) {
      ushort4 w;
      w.x = bfb(Of[n][0] * inv); w.y = bfb(Of[n][1] * inv);
      w.z = bfb(Of[n][2] * inv); w.w = bfb(Of[n][3] * inv);
      *(ushort4*)(Ob + n * 16 + quad * 4) = w;
    }
  }
}

// ---------------- launch ----------------
extern "C" void kernel_launch(void* const* d_in, const int* in_sizes, int n_in,
                              void* d_out, int out_size, void* d_ws, size_t ws_size,
                              hipStream_t stream) {
  const void* x  = d_in[0];
  const void* Wq = d_in[1];
  const void* Wk = d_in[2];
  const void* Wv = d_in[3];
  const void* Wo = d_in[4];
  bf16* ws = (bf16*)d_ws;
  int* flag = (int*)d_ws;

  // workspace (bf16 elem offsets), peak 23,068,688 elems = 46.1 MB (proven)
  bf16* qkv   = ws + 16;        // 4096 x 2560          gemm1 -> rope
  bf16* Vtb   = ws + 10485776;  // 2 x 512 x 2048       gemm1 epilogue -> attn
  bf16* Qb    = ws + 12582928;  // 2x16x2048x128        rope -> attn
  bf16* wqkvT = ws + 12582928;  // 3072x2048 (overlaps Qb; dead before rope writes)
  bf16* Kb    = ws + 20971536;  // 2x4x2048x128         rope -> attn
  bf16* attno = ws + 16;        // reuse qkv            attn -> gemm2
  bf16* woT   = ws + 10485776;  // reuse Vtb/Qb region  (transposed after attn)

  dim3 tb(32, 8);
  detect_dtype<<<1, 256, 0, stream>>>((const unsigned*)x, flag);
  transpose_qkvw<<<dim3(64, 64, 3), tb, 0, stream>>>(Wq, Wk, Wv, wqkvT, flag);
  // qkv = x @ [Wq|Wk|Wv]; q,k cols -> qkv (ldc 2560), v cols -> Vtb transposed
  gemm_bt<<<dim3(QKVW / BN, (B_ * S_) / BM), 256, 0, stream>>>(
      x, wqkvT, qkv, B_ * S_, QKVW, D_, QKW, QKW, Vtb, QKW, flag, 1, 0);
  rope_scatter<<<B_ * S_, 256, 0, stream>>>(qkv, Qb, Kb);
  // paired-causal 1-D grid: 512 blocks; low 3 bits = (b,kh) -> XCD partition
  attn_kernel<<<dim3(512, 1, 1), 256, 0, stream>>>(Qb, Kb, Vtb, attno);
  transpose_cvt<<<dim3(64, 64, 1), tb, 0, stream>>>(Wo, woT, 2048, 2048, flag);
  // out = attno @ Wo (output dtype per flag)
  gemm_bt<<<dim3(D_ / BN, (B_ * S_) / BM), 256, 0, stream>>>(
      attno, woT, d_out, B_ * S_, D_, D_, D_, D_, nullptr, 0, flag, 0, 1);
}

// Round 9
// 380.025 us; speedup vs baseline: 1.1580x; 1.0078x over previous
//
#include <hip/hip_runtime.h>

typedef __bf16 bf16;
typedef __bf16 bf16x8 __attribute__((ext_vector_type(8)));
typedef float f32x4 __attribute__((ext_vector_type(4)));
typedef short s16x4 __attribute__((ext_vector_type(4)));

#define B_ 2
#define S_ 2048
#define D_ 2048
#define H_ 16
#define HKV_ 4
#define HD_ 128
#define QKVW 3072
#define QKW 2560                    // q+k columns (V handled separately)
#define SCALE 0.08838834764831845f  // 1/sqrt(128)
#define NEGINF -30000.0f            // finite -inf: exp underflows to 0, no inf-inf

// async global->LDS DMA, 16B per lane; LDS dest = wave-uniform base + lane*16
__device__ inline void gload16(const void* g, void* l) {
  __builtin_amdgcn_global_load_lds((const __attribute__((address_space(1))) unsigned int*)g,
                                   (__attribute__((address_space(3))) unsigned int*)l, 16, 0, 0);
}

__device__ inline unsigned short bfb(float v) {
  union { bf16 h; unsigned short u; } c;
  c.h = (bf16)v;
  return c.u;
}

// ---------------- dtype detection: bf16 or fp32 inputs? ----------------
__global__ void detect_dtype(const unsigned* __restrict__ xw, int* __restrict__ flag) {
  __shared__ int cnt;
  if (threadIdx.x == 0) cnt = 0;
  __syncthreads();
  unsigned w = xw[(size_t)threadIdx.x * 16384];
  unsigned low = w & 0xFFFFu;
  int e = (int)((low >> 7) & 0xFF);
  int vote = (low == 0u || (e >= 100 && e <= 140)) ? 1 : 0;
  atomicAdd(&cnt, vote);
  __syncthreads();
  if (threadIdx.x == 0) *flag = (cnt >= 128) ? 1 : 0;  // 1 = bf16, 0 = fp32
}

// ---------------- fused Wq/Wk/Wv transpose -> wqkvT (B^T layout) ----------------
__global__ __launch_bounds__(256) void transpose_qkvw(
    const void* __restrict__ Wq, const void* __restrict__ Wk, const void* __restrict__ Wv,
    bf16* __restrict__ wqkvT, const int* __restrict__ flag) {
  int z = blockIdx.z;
  const void* in = (z == 0) ? Wq : (z == 1) ? Wk : Wv;
  int cols = (z == 0) ? 2048 : 512;
  bf16* out = wqkvT + ((z == 0) ? 0 : (z == 1) ? 2048 * 2048 : 2560 * 2048);
  if (blockIdx.x * 32 >= cols) return;
  int fm = *flag;
  __shared__ float tile[32][33];
  int c0 = blockIdx.x * 32, r0 = blockIdx.y * 32;
  int tx = threadIdx.x, ty = threadIdx.y;  // 32 x 8
#pragma unroll
  for (int i = 0; i < 32; i += 8) {
    long idx = (long)(r0 + ty + i) * cols + c0 + tx;
    tile[ty + i][tx] = fm ? (float)((const bf16*)in)[idx] : ((const float*)in)[idx];
  }
  __syncthreads();
#pragma unroll
  for (int i = 0; i < 32; i += 8)
    out[(long)(c0 + ty + i) * 2048 + r0 + tx] = (bf16)tile[tx][ty + i];
}

// ---------------- generic transpose (+dtype-adaptive read) for Wo ----------------
__global__ __launch_bounds__(256) void transpose_cvt(
    const void* __restrict__ in, bf16* __restrict__ out,
    long in_stride, long out_stride, const int* __restrict__ flag) {
  __shared__ float tile[32][33];
  int fm = *flag;
  int c0 = blockIdx.x * 32, r0 = blockIdx.y * 32;
  int tx = threadIdx.x, ty = threadIdx.y;
#pragma unroll
  for (int i = 0; i < 32; i += 8) {
    long idx = (long)(r0 + ty + i) * in_stride + c0 + tx;
    tile[ty + i][tx] = fm ? (float)((const bf16*)in)[idx] : ((const float*)in)[idx];
  }
  __syncthreads();
#pragma unroll
  for (int i = 0; i < 32; i += 8)
    out[(long)(c0 + ty + i) * out_stride + r0 + tx] = (bf16)tile[tx][ty + i];
}

// ---------------- GEMM (gemm2 config): C = A * Bt^T, 128x128, 256 thr ----------------
// R7/R8 kernel unchanged (proven): 2-phase dbuf, BK=32, 32 KB LDS, one __syncthreads
// per K-step, mod-4 rotation swizzle both-sides (bank conflicts = 0), T1 XCD swizzle.
#define BM 128
#define BN 128
#define BK 32

__global__ __launch_bounds__(256) void gemm_bt(
    const void* __restrict__ A, const bf16* __restrict__ Bt, void* __restrict__ C,
    int M, int N, int K, int ldc, int ncmax,
    bf16* __restrict__ vt_out, int vcol0,
    const int* __restrict__ flag, int adyn, int cdyn) {
  alignas(16) __shared__ bf16 la[2 * BM * BK];  // 2 x 8 KB, unpadded (DMA lane-linear)
  alignas(16) __shared__ bf16 lb[2 * BN * BK];  // 2 x 8 KB
  int fm = flag ? *flag : 1;
  bool af32 = adyn && !fm;
  bool cf32 = cdyn && !fm;
  int tid = threadIdx.x;
  int wave = tid >> 6, lane = tid & 63;
  int wr = wave >> 1, wc = wave & 1;
  int quad = lane >> 4, l16 = lane & 15;

  // T1: XCD-aware block swizzle (nwg % 8 == 0 for both launches)
  int nwg = (int)(gridDim.x * gridDim.y);
  int flat = (int)(blockIdx.y * gridDim.x + blockIdx.x);
  int cpx = nwg >> 3;
  int wk = (flat & 7) * cpx + (flat >> 3);
  int bx = wk % (int)gridDim.x, by = wk / (int)gridDim.x;
  int m0 = by * BM, n0 = bx * BN;

  f32x4 acc[4][4] = {};

  int sr = (wave << 4) + (lane >> 2);
  int sc = (((lane & 3) - (sr >> 1)) & 3) << 3;  // rotated source chunk (elems)
  const bf16* gb0 = Bt + (long)(n0 + sr) * K + sc;
  const bf16* gb1 = Bt + (long)(n0 + 64 + sr) * K + sc;
  int lo0 = (wave << 9);
  int lo1 = 2048 + (wave << 9);
  const bf16* ga0 = nullptr; const bf16* ga1 = nullptr;
  const float* gaf = nullptr;
  int fr = tid >> 1, fh = (tid & 1) << 4;
  if (af32) gaf = (const float*)A + (long)(m0 + fr) * K + fh;
  else { ga0 = (const bf16*)A + (long)(m0 + sr) * K + sc;
         ga1 = (const bf16*)A + (long)(m0 + 64 + sr) * K + sc; }
  int c0 = fh >> 3;
  int k2 = (fr >> 1) & 3;
  int ws0 = ((c0 + k2) & 3) << 3;
  int ws1 = ((c0 + 1 + k2) & 3) << 3;

  int nk = K / BK;

  auto cvtwrite = [&](const float4* f, int buf) {
    alignas(16) bf16 tt[16];
#pragma unroll
    for (int u = 0; u < 4; u++) {
      tt[4 * u] = (bf16)f[u].x; tt[4 * u + 1] = (bf16)f[u].y;
      tt[4 * u + 2] = (bf16)f[u].z; tt[4 * u + 3] = (bf16)f[u].w;
    }
    bf16* rowp = la + (buf << 12) + fr * BK;
    *(uint4*)(rowp + ws0) = *(uint4*)tt;
    *(uint4*)(rowp + ws1) = *(uint4*)(tt + 8);
  };
  auto compute = [&](int buf) {
    const bf16* baA = la + (buf << 12);
    const bf16* baB = lb + (buf << 12);
    bf16x8 afr[4], bfr[4];
#pragma unroll
    for (int i = 0; i < 4; i++) {
      int rowA = (wr << 6) + (i << 4) + l16;
      afr[i] = *(const bf16x8*)(baA + rowA * BK + (((quad + (rowA >> 1)) & 3) << 3));
    }
#pragma unroll
    for (int j = 0; j < 4; j++) {
      int rowB = (wc << 6) + (j << 4) + l16;
      bfr[j] = *(const bf16x8*)(baB + rowB * BK + (((quad + (rowB >> 1)) & 3) << 3));
    }
#pragma unroll
    for (int i = 0; i < 4; i++)
#pragma unroll
      for (int j = 0; j < 4; j++)
        acc[i][j] = __builtin_amdgcn_mfma_f32_16x16x32_bf16(afr[i], bfr[j], acc[i][j], 0, 0, 0);
  };

  gload16(gb0, lb + lo0);
  gload16(gb1, lb + lo1);
  if (af32) {
    float4 f0[4];
#pragma unroll
    for (int u = 0; u < 4; u++) f0[u] = *(const float4*)(gaf + 4 * u);
    cvtwrite(f0, 0);
  } else {
    gload16(ga0, la + lo0);
    gload16(ga1, la + lo1);
  }
  __syncthreads();

  for (int t = 0; t < nk; ++t) {
    int cur = t & 1, nxt = cur ^ 1;
    bool hasnext = (t + 1 < nk);
    float4 f[4];
    if (hasnext) {
      int k0 = (t + 1) * BK;
      gload16(gb0 + k0, lb + (nxt << 12) + lo0);
      gload16(gb1 + k0, lb + (nxt << 12) + lo1);
      if (af32) {
        const float* fp = gaf + k0;
#pragma unroll
        for (int u = 0; u < 4; u++) f[u] = *(const float4*)(fp + 4 * u);
      } else {
        gload16(ga0 + k0, la + (nxt << 12) + lo0);
        gload16(ga1 + k0, la + (nxt << 12) + lo1);
      }
    }

    compute(cur);

    if (hasnext && af32) cvtwrite(f, nxt);
    __syncthreads();
  }

  if (vt_out && n0 >= vcol0) {
#pragma unroll
    for (int i = 0; i < 4; i++)
#pragma unroll
      for (int j = 0; j < 4; j++) {
        int col = n0 + (wc << 6) + (j << 4) + l16;
        int hdg = col - vcol0;
        int row0 = m0 + (wr << 6) + (i << 4) + (quad << 2);
        int bb = row0 >> 11, s = row0 & 2047;
        ushort4 p;
        p.x = bfb(acc[i][j][0]); p.y = bfb(acc[i][j][1]);
        p.z = bfb(acc[i][j][2]); p.w = bfb(acc[i][j][3]);
        *(ushort4*)(vt_out + (((long)(bb * 512 + hdg)) << 11) + s) = p;
      }
  } else {
#pragma unroll
    for (int i = 0; i < 4; i++)
#pragma unroll
      for (int j = 0; j < 4; j++) {
        int col = n0 + (wc << 6) + (j << 4) + l16;
        if (col >= ncmax) continue;
#pragma unroll
        for (int r = 0; r < 4; r++) {
          long row = m0 + (wr << 6) + (i << 4) + (quad << 2) + r;
          float v = acc[i][j][r];
          if (cf32) ((float*)C)[row * ldc + col] = v;
          else      ((bf16*)C)[row * ldc + col] = (bf16)v;
        }
      }
  }
}

// ---------------- GEMM wide (gemm1): 128M x 256N, BK=32, 512 thr / 8 waves ----------------
// Same proven 2-phase skeleton + rotation swizzle; BN=256 halves A-panel re-reads
// (N/BN 24->12) and cuts per-FLOP LDS-fill traffic 23->15 B/kFLOP (L2-BW diagnosis).
// Wave grid 2M x 4N -> per-wave 64x64 output = identical acc[4][4] inner code.
// LDS 48 KB -> 2 blocks/CU x 8 waves = 16 waves/CU. Grid 12x32 = 384 (%8==0).
#define WBM 128
#define WBN 256
#define WBK 32

__global__ __launch_bounds__(512, 4) void gemm_bt_wide(
    const void* __restrict__ A, const bf16* __restrict__ Bt, bf16* __restrict__ C,
    int K, int ldc, int ncmax,
    bf16* __restrict__ vt_out, int vcol0, const int* __restrict__ flag) {
  alignas(16) __shared__ bf16 la[2 * WBM * WBK];  // 2 x 8 KB
  alignas(16) __shared__ bf16 lb[2 * WBN * WBK];  // 2 x 16 KB  (48 KB total)
  int fm = flag ? *flag : 1;
  bool af32 = !fm;  // A = x: fp32 unless inputs are bf16
  int tid = threadIdx.x;
  int wave = tid >> 6, lane = tid & 63;
  int wm = wave >> 2, wn = wave & 3;  // 2M x 4N wave grid
  int quad = lane >> 4, l16 = lane & 15;

  // T1: XCD-aware block swizzle (384 % 8 == 0)
  int nwg = (int)(gridDim.x * gridDim.y);
  int flat = (int)(blockIdx.y * gridDim.x + blockIdx.x);
  int cpx = nwg >> 3;
  int wk = (flat & 7) * cpx + (flat >> 3);
  int bx = wk % (int)gridDim.x, by = wk / (int)gridDim.x;
  int m0 = by * WBM, n0 = bx * WBN;

  f32x4 acc[4][4] = {};

  // B staging: 2 gload16/wave; call u covers rows wave*32 + u*16 + (lane>>2)
  const bf16* gb[2];
  int lbo[2];
#pragma unroll
  for (int u = 0; u < 2; u++) {
    int sr2 = (wave << 5) + (u << 4) + (lane >> 2);
    int sc2 = (((lane & 3) - (sr2 >> 1)) & 3) << 3;  // rotated source chunk
    gb[u] = Bt + (long)(n0 + sr2) * K + sc2;
    lbo[u] = ((wave << 5) + (u << 4)) << 5;  // row_base * 32 elems (lane-linear dest)
  }
  // A staging: bf16 path = 1 gload16/wave (rows wave*16 + lane>>2);
  //            fp32 path = per-thread 8 floats, row tid>>2, chunk tid&3
  const bf16* gaB = nullptr;
  const float* gaf = nullptr;
  int lao = (wave << 4) << 5;
  int fr = tid >> 2, fc = tid & 3;
  int wso = 0;
  if (af32) {
    gaf = (const float*)A + (long)(m0 + fr) * K + (fc << 3);
    wso = (fr << 5) + ((((fc) + (fr >> 1)) & 3) << 3);  // rotated write slot
  } else {
    int ra = (wave << 4) + (lane >> 2);
    int sca = (((lane & 3) - (ra >> 1)) & 3) << 3;
    gaB = (const bf16*)A + (long)(m0 + ra) * K + sca;
  }

  int nk = K / WBK;

  auto cvtwrite = [&](const float4* f, int buf) {
    alignas(16) bf16 tt[8];
    tt[0] = (bf16)f[0].x; tt[1] = (bf16)f[0].y; tt[2] = (bf16)f[0].z; tt[3] = (bf16)f[0].w;
    tt[4] = (bf16)f[1].x; tt[5] = (bf16)f[1].y; tt[6] = (bf16)f[1].z; tt[7] = (bf16)f[1].w;
    *(uint4*)(la + (buf << 12) + wso) = *(uint4*)tt;
  };
  auto compute = [&](int buf) {
    const bf16* baA = la + (buf << 12);
    const bf16* baB = lb + (buf << 13);
    bf16x8 afr[4], bfr[4];
#pragma unroll
    for (int i = 0; i < 4; i++) {
      int rowA = (wm << 6) + (i << 4) + l16;
      afr[i] = *(const bf16x8*)(baA + (rowA << 5) + (((quad + (rowA >> 1)) & 3) << 3));
    }
#pragma unroll
    for (int j = 0; j < 4; j++) {
      int rowB = (wn << 6) + (j << 4) + l16;
      bfr[j] = *(const bf16x8*)(baB + (rowB << 5) + (((quad + (rowB >> 1)) & 3) << 3));
    }
#pragma unroll
    for (int i = 0; i < 4; i++)
#pragma unroll
      for (int j = 0; j < 4; j++)
        acc[i][j] = __builtin_amdgcn_mfma_f32_16x16x32_bf16(afr[i], bfr[j], acc[i][j], 0, 0, 0);
  };

  // ---- prologue: stage tile 0 into buffer 0 ----
  gload16(gb[0], lb + lbo[0]);
  gload16(gb[1], lb + lbo[1]);
  if (af32) {
    float4 f0[2];
    f0[0] = *(const float4*)gaf;
    f0[1] = *(const float4*)(gaf + 4);
    cvtwrite(f0, 0);
  } else {
    gload16(gaB, la + lao);
  }
  __syncthreads();

  // ---- main loop: ONE barrier per K-step; stage t+1 overlaps compute t ----
  for (int t = 0; t < nk; ++t) {
    int cur = t & 1, nxt = cur ^ 1;
    bool hasnext = (t + 1 < nk);
    float4 f[2];
    if (hasnext) {
      int k0 = (t + 1) * WBK;
      gload16(gb[0] + k0, lb + (nxt << 13) + lbo[0]);
      gload16(gb[1] + k0, lb + (nxt << 13) + lbo[1]);
      if (af32) {
        f[0] = *(const float4*)(gaf + k0);
        f[1] = *(const float4*)(gaf + k0 + 4);
      } else {
        gload16(gaB + k0, la + (nxt << 12) + lao);
      }
    }

    compute(cur);

    if (hasnext && af32) cvtwrite(f, nxt);  // f32 loads landed during MFMA
    __syncthreads();
  }

  // epilogue: col = n0 + wn*64 + j*16 + l16; row = m0 + wm*64 + i*16 + quad*4 + r
  if (vt_out && n0 >= vcol0) {
#pragma unroll
    for (int i = 0; i < 4; i++)
#pragma unroll
      for (int j = 0; j < 4; j++) {
        int col = n0 + (wn << 6) + (j << 4) + l16;
        int hdg = col - vcol0;                            // 0..511 = kh*128+hd
        int row0 = m0 + (wm << 6) + (i << 4) + (quad << 2);
        int bb = row0 >> 11, s = row0 & 2047;
        ushort4 p;
        p.x = bfb(acc[i][j][0]); p.y = bfb(acc[i][j][1]);
        p.z = bfb(acc[i][j][2]); p.w = bfb(acc[i][j][3]);
        *(ushort4*)(vt_out + (((long)(bb * 512 + hdg)) << 11) + s) = p;
      }
  } else {
#pragma unroll
    for (int i = 0; i < 4; i++)
#pragma unroll
      for (int j = 0; j < 4; j++) {
        int col = n0 + (wn << 6) + (j << 4) + l16;
        if (col >= ncmax) continue;
#pragma unroll
        for (int r = 0; r < 4; r++) {
          long row = m0 + (wm << 6) + (i << 4) + (quad << 2) + r;
          C[row * ldc + col] = (bf16)acc[i][j][r];
        }
      }
  }
}

// ---------------- RoPE + scatter (Q pre-scaled by 1/sqrt(d)) ----------------
__global__ __launch_bounds__(256) void rope_scatter(
    const bf16* __restrict__ qkv, bf16* __restrict__ Q, bf16* __restrict__ Ko) {
  int row = blockIdx.x;  // b*S + s
  int b = row >> 11, s = row & 2047;
  int tid = threadIdx.x;
  int i = tid & 63;
  const bf16* src = qkv + (long)row * QKW;
  float theta = __expf(-0.14391156831212787f * (float)i);  // 10000^(-2i/128)
  float sn, cs;
  sincosf((float)s * theta, &sn, &cs);
#pragma unroll
  for (int it = 0; it < 4; ++it) {
    int h = (tid + it * 256) >> 6;  // 0..15 over the 4 iterations
    unsigned v = *(const unsigned*)(src + h * 128 + 2 * i);
    float x1 = __uint_as_float(v << 16);
    float x2 = __uint_as_float(v & 0xFFFF0000u);
    long qb = ((long)(b * H_ + h) * S_ + s) * HD_;
    Q[qb + i]      = (bf16)((x1 * cs - x2 * sn) * SCALE);
    Q[qb + 64 + i] = (bf16)((x1 * sn + x2 * cs) * SCALE);
  }
  {
    int kh = tid >> 6;
    unsigned v = *(const unsigned*)(src + 2048 + kh * 128 + 2 * i);
    float x1 = __uint_as_float(v << 16);
    float x2 = __uint_as_float(v & 0xFFFF0000u);
    long kb = ((long)(b * HKV_ + kh) * S_ + s) * HD_;
    Ko[kb + i]      = (bf16)(x1 * cs - x2 * sn);
    Ko[kb + 64 + i] = (bf16)(x1 * sn + x2 * cs);
  }
}

// ---------------- flash attention (R8 version, unchanged) ----------------
#define KTILE 8192  // 64 rows x 128 elems
#define VTILE 8192  // 128 rows x 64 elems

__global__ __launch_bounds__(256) void attn_kernel(
    const bf16* __restrict__ Q, const bf16* __restrict__ K,
    const bf16* __restrict__ Vt, bf16* __restrict__ O) {
  alignas(16) __shared__ bf16 Ks[2 * KTILE];  // 32 KB
  alignas(16) __shared__ bf16 Vs[2 * VTILE];  // 32 KB
  int bi = (int)blockIdx.x;        // 512 blocks, 1-D
  int cb = bi & 7;                 // XCD selector = (b, kh)
  int b = cb >> 2, kh = cb & 3;
  int r = bi >> 3;
  int qt0 = r >> 2;                // 0..15; paired with 31-qt0
  int h = kh * 4 + (r & 3);
  int tid = threadIdx.x, wave = tid >> 6, lane = tid & 63;
  int quad = lane >> 4, l16 = lane & 15;
  const bf16* Kg = K + ((long)(b * HKV_ + kh) * S_) * HD_;
  const bf16* Vg = Vt + ((long)(b * HKV_ + kh) * HD_) * S_;

  int kgo[4], vgo[4], klo[4], vlo[4];
#pragma unroll
  for (int u = 0; u < 4; u++) {
    int i = u * 4 + wave;
    int rr = i * 4 + quad;
    int c = l16 ^ (rr & 15);
    kgo[u] = rr * HD_ + c * 8;
    klo[u] = i * 512;
    int v = i * 8 + (lane >> 3);
    int cv = (lane & 7) ^ (v & 7);
    vgo[u] = v * S_ + cv * 8;
    vlo[u] = i * 512;
  }

  for (int hf = 0; hf < 2; ++hf) {
    int qt = hf ? 31 - qt0 : qt0;
    int q0 = qt * 64;
    const bf16* Qg = Q + ((long)(b * H_ + h) * S_ + q0) * HD_;

    bf16x8 qb[4];
    {
      const bf16* qrow = Qg + (wave * 16 + l16) * HD_ + quad * 8;
#pragma unroll
      for (int kk = 0; kk < 4; kk++) qb[kk] = *(const bf16x8*)(qrow + kk * 32);
    }

    if (hf) __syncthreads();

#pragma unroll
    for (int u = 0; u < 4; u++) {
      gload16(Kg + kgo[u], Ks + klo[u]);
      gload16(Vg + vgo[u], Vs + vlo[u]);
    }

    f32x4 Of[8] = {};
    float m_run = NEGINF, l_run = 0.f;

    for (int kt = 0; kt <= qt; ++kt) {
      __syncthreads();
      int p = kt & 1;
      if (kt < qt) {
        const bf16* kn = Kg + (long)(kt + 1) * 8192;
        const bf16* vn = Vg + (long)(kt + 1) * 64;
        bf16* kd = Ks + (p ^ 1) * KTILE;
        bf16* vd = Vs + (p ^ 1) * VTILE;
#pragma unroll
        for (int u = 0; u < 4; u++) {
          gload16(kn + kgo[u], kd + klo[u]);
          gload16(vn + vgo[u], vd + vlo[u]);
        }
      }
      const bf16* kc = Ks + p * KTILE;
      const bf16* vc = Vs + p * VTILE;

      bool diag = (kt == qt);
      f32x4 sf[4];
      __builtin_amdgcn_s_setprio(1);
#pragma unroll
      for (int jb = 0; jb < 4; jb++) {
        if (diag && jb > wave) {
          sf[jb] = (f32x4){NEGINF, NEGINF, NEGINF, NEGINF};
        } else {
          f32x4 a = {};
          const bf16* kbase = kc + (jb * 16 + l16) * 128;
#pragma unroll
          for (int kk = 0; kk < 4; kk++) {
            bf16x8 kf = *(const bf16x8*)(kbase + (((kk * 4 + quad) ^ l16) * 8));
            a = __builtin_amdgcn_mfma_f32_16x16x32_bf16(kf, qb[kk], a, 0, 0, 0);
          }
          sf[jb] = a;
        }
      }
      __builtin_amdgcn_s_setprio(0);
      if (diag) {
#pragma unroll
        for (int jb = 0; jb < 4; jb++)
          if (jb == wave) {
#pragma unroll
            for (int r2 = 0; r2 < 4; r2++)
              if (quad * 4 + r2 > l16) sf[jb][r2] = NEGINF;
          }
      }

      float mx = NEGINF;
#pragma unroll
      for (int jb = 0; jb < 4; jb++)
#pragma unroll
        for (int r2 = 0; r2 < 4; r2++) mx = fmaxf(mx, sf[jb][r2]);
      mx = fmaxf(mx, __shfl_xor(mx, 16));
      mx = fmaxf(mx, __shfl_xor(mx, 32));
      if (__any(mx > m_run + 8.0f)) {
        float mnew = fmaxf(m_run, mx);
        float alpha = __expf(m_run - mnew);
        m_run = mnew;
        l_run *= alpha;
#pragma unroll
        for (int n = 0; n < 8; n++) Of[n] *= alpha;
      }

      float ls = 0.f;
      s16x4 pk[4];
#pragma unroll
      for (int jb = 0; jb < 4; jb++) {
        float p0 = __expf(sf[jb][0] - m_run);
        float p1 = __expf(sf[jb][1] - m_run);
        float p2 = __expf(sf[jb][2] - m_run);
        float p3 = __expf(sf[jb][3] - m_run);
        ls += (p0 + p1) + (p2 + p3);
        s16x4 t;
        t.x = (short)bfb(p0); t.y = (short)bfb(p1);
        t.z = (short)bfb(p2); t.w = (short)bfb(p3);
        pk[jb] = t;
      }
      l_run += ls;

      __builtin_amdgcn_s_setprio(1);
#pragma unroll
      for (int jb = 0; jb < 4; jb++) {
        if (diag && jb > wave) continue;
#pragma unroll
        for (int n = 0; n < 8; n++) {
          int v = n * 16 + l16;
          const bf16* va_p = vc + v * 64 + (((jb * 2 + (quad >> 1)) ^ (l16 & 7)) * 8) + (quad & 1) * 4;
          s16x4 va = *(const s16x4*)va_p;
          Of[n] = __builtin_amdgcn_mfma_f32_16x16x16bf16_1k(va, pk[jb], Of[n], 0, 0, 0);
        }
      }
      __builtin_amdgcn_s_setprio(0);
    }

    l_run += __shfl_xor(l_run, 16);
    l_run += __shfl_xor(l_run, 32);
    float inv = 1.0f / fmaxf(l_run, 1e-30f);
    bf16* Ob = O + ((long)(b * S_) + q0 + wave * 16 + l16) * D_ + h * HD_;
#pragma unroll
    for (int n = 0; n < 8; n++) {
      ushort4 w;
      w.x = bfb(Of[n][0] * inv); w.y = bfb(Of[n][1] * inv);
      w.z = bfb(Of[n][2] * inv); w.w = bfb(Of[n][3] * inv);
      *(ushort4*)(Ob + n * 16 + quad * 4) = w;
    }
  }
}

// ---------------- launch ----------------
extern "C" void kernel_launch(void* const* d_in, const int* in_sizes, int n_in,
                              void* d_out, int out_size, void* d_ws, size_t ws_size,
                              hipStream_t stream) {
  const void* x  = d_in[0];
  const void* Wq = d_in[1];
  const void* Wk = d_in[2];
  const void* Wv = d_in[3];
  const void* Wo = d_in[4];
  bf16* ws = (bf16*)d_ws;
  int* flag = (int*)d_ws;

  // workspace (bf16 elem offsets), peak 23,068,688 elems = 46.1 MB (proven)
  bf16* qkv   = ws + 16;        // 4096 x 2560          gemm1 -> rope
  bf16* Vtb   = ws + 10485776;  // 2 x 512 x 2048       gemm1 epilogue -> attn
  bf16* Qb    = ws + 12582928;  // 2x16x2048x128        rope -> attn
  bf16* wqkvT = ws + 12582928;  // 3072x2048 (overlaps Qb; dead before rope writes)
  bf16* Kb    = ws + 20971536;  // 2x4x2048x128         rope -> attn
  bf16* attno = ws + 16;        // reuse qkv            attn -> gemm2
  bf16* woT   = ws + 10485776;  // reuse Vtb/Qb region  (transposed after attn)

  dim3 tb(32, 8);
  detect_dtype<<<1, 256, 0, stream>>>((const unsigned*)x, flag);
  transpose_qkvw<<<dim3(64, 64, 3), tb, 0, stream>>>(Wq, Wk, Wv, wqkvT, flag);
  // qkv = x @ [Wq|Wk|Wv]; q,k cols -> qkv (ldc 2560), v cols -> Vtb transposed
  gemm_bt_wide<<<dim3(QKVW / WBN, (B_ * S_) / WBM), 512, 0, stream>>>(
      x, wqkvT, qkv, D_, QKW, QKW, Vtb, QKW, flag);
  rope_scatter<<<B_ * S_, 256, 0, stream>>>(qkv, Qb, Kb);
  // paired-causal 1-D grid: 512 blocks; low 3 bits = (b,kh) -> XCD partition
  attn_kernel<<<dim3(512, 1, 1), 256, 0, stream>>>(Qb, Kb, Vtb, attno);
  transpose_cvt<<<dim3(64, 64, 1), tb, 0, stream>>>(Wo, woT, 2048, 2048, flag);
  // out = attno @ Wo (output dtype per flag)
  gemm_bt<<<dim3(D_ / BN, (B_ * S_) / BM), 256, 0, stream>>>(
      attno, woT, d_out, B_ * S_, D_, D_, D_, D_, nullptr, 0, flag, 0, 1);
}

// Round 10
// 369.954 us; speedup vs baseline: 1.1896x; 1.0272x over previous
//
#include <hip/hip_runtime.h>

typedef __bf16 bf16;
typedef __bf16 bf16x8 __attribute__((ext_vector_type(8)));
typedef float f32x4 __attribute__((ext_vector_type(4)));
typedef short s16x4 __attribute__((ext_vector_type(4)));

#define B_ 2
#define S_ 2048
#define D_ 2048
#define H_ 16
#define HKV_ 4
#define HD_ 128
#define QKVW 3072
#define QKW 2560                    // q+k columns (V handled separately)
#define SCALE 0.08838834764831845f  // 1/sqrt(128)
#define NEGINF -30000.0f            // finite -inf: exp underflows to 0, no inf-inf

// async global->LDS DMA, 16B per lane; LDS dest = wave-uniform base + lane*16
__device__ inline void gload16(const void* g, void* l) {
  __builtin_amdgcn_global_load_lds((const __attribute__((address_space(1))) unsigned int*)g,
                                   (__attribute__((address_space(3))) unsigned int*)l, 16, 0, 0);
}

__device__ inline unsigned short bfb(float v) {
  union { bf16 h; unsigned short u; } c;
  c.h = (bf16)v;
  return c.u;
}

// ---------------- dtype detection: bf16 or fp32 inputs? ----------------
__global__ void detect_dtype(const unsigned* __restrict__ xw, int* __restrict__ flag) {
  __shared__ int cnt;
  if (threadIdx.x == 0) cnt = 0;
  __syncthreads();
  unsigned w = xw[(size_t)threadIdx.x * 16384];
  unsigned low = w & 0xFFFFu;
  int e = (int)((low >> 7) & 0xFF);
  int vote = (low == 0u || (e >= 100 && e <= 140)) ? 1 : 0;
  atomicAdd(&cnt, vote);
  __syncthreads();
  if (threadIdx.x == 0) *flag = (cnt >= 128) ? 1 : 0;  // 1 = bf16, 0 = fp32
}

// ---------------- x -> bf16 pre-cast (into d_out scratch) ----------------
// Moves the fp32->bf16 conversion OUT of gemm1's per-K-step critical path (the
// wait->cvt->ds_write tail sat right before each barrier). Flag-adaptive:
// fp32 -> convert, bf16 -> copy. d_out is legal scratch: it is written only by
// gemm2, which runs strictly after gemm1's reads on the same stream, and
// out elems == x elems so it always fits.
__global__ __launch_bounds__(256) void cast_x(const void* __restrict__ x,
                                              bf16* __restrict__ out,
                                              const int* __restrict__ flag) {
  int fm = *flag;
  long i = ((long)blockIdx.x * 256 + threadIdx.x) << 3;  // 8 elems/thread
  if (fm) {
    *(uint4*)(out + i) = *(const uint4*)((const bf16*)x + i);
  } else {
    const float* fp = (const float*)x + i;
    float4 a = *(const float4*)fp, b = *(const float4*)(fp + 4);
    alignas(16) bf16 t[8];
    t[0] = (bf16)a.x; t[1] = (bf16)a.y; t[2] = (bf16)a.z; t[3] = (bf16)a.w;
    t[4] = (bf16)b.x; t[5] = (bf16)b.y; t[6] = (bf16)b.z; t[7] = (bf16)b.w;
    *(uint4*)(out + i) = *(uint4*)t;
  }
}

// ---------------- fused Wq/Wk/Wv transpose -> wqkvT (B^T layout) ----------------
__global__ __launch_bounds__(256) void transpose_qkvw(
    const void* __restrict__ Wq, const void* __restrict__ Wk, const void* __restrict__ Wv,
    bf16* __restrict__ wqkvT, const int* __restrict__ flag) {
  int z = blockIdx.z;
  const void* in = (z == 0) ? Wq : (z == 1) ? Wk : Wv;
  int cols = (z == 0) ? 2048 : 512;
  bf16* out = wqkvT + ((z == 0) ? 0 : (z == 1) ? 2048 * 2048 : 2560 * 2048);
  if (blockIdx.x * 32 >= cols) return;
  int fm = *flag;
  __shared__ float tile[32][33];
  int c0 = blockIdx.x * 32, r0 = blockIdx.y * 32;
  int tx = threadIdx.x, ty = threadIdx.y;  // 32 x 8
#pragma unroll
  for (int i = 0; i < 32; i += 8) {
    long idx = (long)(r0 + ty + i) * cols + c0 + tx;
    tile[ty + i][tx] = fm ? (float)((const bf16*)in)[idx] : ((const float*)in)[idx];
  }
  __syncthreads();
#pragma unroll
  for (int i = 0; i < 32; i += 8)
    out[(long)(c0 + ty + i) * 2048 + r0 + tx] = (bf16)tile[tx][ty + i];
}

// ---------------- generic transpose (+dtype-adaptive read) for Wo ----------------
__global__ __launch_bounds__(256) void transpose_cvt(
    const void* __restrict__ in, bf16* __restrict__ out,
    long in_stride, long out_stride, const int* __restrict__ flag) {
  __shared__ float tile[32][33];
  int fm = *flag;
  int c0 = blockIdx.x * 32, r0 = blockIdx.y * 32;
  int tx = threadIdx.x, ty = threadIdx.y;
#pragma unroll
  for (int i = 0; i < 32; i += 8) {
    long idx = (long)(r0 + ty + i) * in_stride + c0 + tx;
    tile[ty + i][tx] = fm ? (float)((const bf16*)in)[idx] : ((const float*)in)[idx];
  }
  __syncthreads();
#pragma unroll
  for (int i = 0; i < 32; i += 8)
    out[(long)(c0 + ty + i) * out_stride + r0 + tx] = (bf16)tile[tx][ty + i];
}

// ---------------- GEMM (gemm2 config): C = A * Bt^T, 128x128, 256 thr ----------------
// R7/R8 kernel unchanged (proven): 2-phase dbuf, BK=32, 32 KB LDS, one __syncthreads
// per K-step, mod-4 rotation swizzle both-sides (bank conflicts = 0), T1 XCD swizzle.
#define BM 128
#define BN 128
#define BK 32

__global__ __launch_bounds__(256) void gemm_bt(
    const void* __restrict__ A, const bf16* __restrict__ Bt, void* __restrict__ C,
    int M, int N, int K, int ldc, int ncmax,
    bf16* __restrict__ vt_out, int vcol0,
    const int* __restrict__ flag, int adyn, int cdyn) {
  alignas(16) __shared__ bf16 la[2 * BM * BK];  // 2 x 8 KB, unpadded (DMA lane-linear)
  alignas(16) __shared__ bf16 lb[2 * BN * BK];  // 2 x 8 KB
  int fm = flag ? *flag : 1;
  bool af32 = adyn && !fm;
  bool cf32 = cdyn && !fm;
  int tid = threadIdx.x;
  int wave = tid >> 6, lane = tid & 63;
  int wr = wave >> 1, wc = wave & 1;
  int quad = lane >> 4, l16 = lane & 15;

  // T1: XCD-aware block swizzle (nwg % 8 == 0 for both launches)
  int nwg = (int)(gridDim.x * gridDim.y);
  int flat = (int)(blockIdx.y * gridDim.x + blockIdx.x);
  int cpx = nwg >> 3;
  int wk = (flat & 7) * cpx + (flat >> 3);
  int bx = wk % (int)gridDim.x, by = wk / (int)gridDim.x;
  int m0 = by * BM, n0 = bx * BN;

  f32x4 acc[4][4] = {};

  int sr = (wave << 4) + (lane >> 2);
  int sc = (((lane & 3) - (sr >> 1)) & 3) << 3;  // rotated source chunk (elems)
  const bf16* gb0 = Bt + (long)(n0 + sr) * K + sc;
  const bf16* gb1 = Bt + (long)(n0 + 64 + sr) * K + sc;
  int lo0 = (wave << 9);
  int lo1 = 2048 + (wave << 9);
  const bf16* ga0 = nullptr; const bf16* ga1 = nullptr;
  const float* gaf = nullptr;
  int fr = tid >> 1, fh = (tid & 1) << 4;
  if (af32) gaf = (const float*)A + (long)(m0 + fr) * K + fh;
  else { ga0 = (const bf16*)A + (long)(m0 + sr) * K + sc;
         ga1 = (const bf16*)A + (long)(m0 + 64 + sr) * K + sc; }
  int c0 = fh >> 3;
  int k2 = (fr >> 1) & 3;
  int ws0 = ((c0 + k2) & 3) << 3;
  int ws1 = ((c0 + 1 + k2) & 3) << 3;

  int nk = K / BK;

  auto cvtwrite = [&](const float4* f, int buf) {
    alignas(16) bf16 tt[16];
#pragma unroll
    for (int u = 0; u < 4; u++) {
      tt[4 * u] = (bf16)f[u].x; tt[4 * u + 1] = (bf16)f[u].y;
      tt[4 * u + 2] = (bf16)f[u].z; tt[4 * u + 3] = (bf16)f[u].w;
    }
    bf16* rowp = la + (buf << 12) + fr * BK;
    *(uint4*)(rowp + ws0) = *(uint4*)tt;
    *(uint4*)(rowp + ws1) = *(uint4*)(tt + 8);
  };
  auto compute = [&](int buf) {
    const bf16* baA = la + (buf << 12);
    const bf16* baB = lb + (buf << 12);
    bf16x8 afr[4], bfr[4];
#pragma unroll
    for (int i = 0; i < 4; i++) {
      int rowA = (wr << 6) + (i << 4) + l16;
      afr[i] = *(const bf16x8*)(baA + rowA * BK + (((quad + (rowA >> 1)) & 3) << 3));
    }
#pragma unroll
    for (int j = 0; j < 4; j++) {
      int rowB = (wc << 6) + (j << 4) + l16;
      bfr[j] = *(const bf16x8*)(baB + rowB * BK + (((quad + (rowB >> 1)) & 3) << 3));
    }
#pragma unroll
    for (int i = 0; i < 4; i++)
#pragma unroll
      for (int j = 0; j < 4; j++)
        acc[i][j] = __builtin_amdgcn_mfma_f32_16x16x32_bf16(afr[i], bfr[j], acc[i][j], 0, 0, 0);
  };

  gload16(gb0, lb + lo0);
  gload16(gb1, lb + lo1);
  if (af32) {
    float4 f0[4];
#pragma unroll
    for (int u = 0; u < 4; u++) f0[u] = *(const float4*)(gaf + 4 * u);
    cvtwrite(f0, 0);
  } else {
    gload16(ga0, la + lo0);
    gload16(ga1, la + lo1);
  }
  __syncthreads();

  for (int t = 0; t < nk; ++t) {
    int cur = t & 1, nxt = cur ^ 1;
    bool hasnext = (t + 1 < nk);
    float4 f[4];
    if (hasnext) {
      int k0 = (t + 1) * BK;
      gload16(gb0 + k0, lb + (nxt << 12) + lo0);
      gload16(gb1 + k0, lb + (nxt << 12) + lo1);
      if (af32) {
        const float* fp = gaf + k0;
#pragma unroll
        for (int u = 0; u < 4; u++) f[u] = *(const float4*)(fp + 4 * u);
      } else {
        gload16(ga0 + k0, la + (nxt << 12) + lo0);
        gload16(ga1 + k0, la + (nxt << 12) + lo1);
      }
    }

    compute(cur);

    if (hasnext && af32) cvtwrite(f, nxt);
    __syncthreads();
  }

  if (vt_out && n0 >= vcol0) {
#pragma unroll
    for (int i = 0; i < 4; i++)
#pragma unroll
      for (int j = 0; j < 4; j++) {
        int col = n0 + (wc << 6) + (j << 4) + l16;
        int hdg = col - vcol0;
        int row0 = m0 + (wr << 6) + (i << 4) + (quad << 2);
        int bb = row0 >> 11, s = row0 & 2047;
        ushort4 p;
        p.x = bfb(acc[i][j][0]); p.y = bfb(acc[i][j][1]);
        p.z = bfb(acc[i][j][2]); p.w = bfb(acc[i][j][3]);
        *(ushort4*)(vt_out + (((long)(bb * 512 + hdg)) << 11) + s) = p;
      }
  } else {
#pragma unroll
    for (int i = 0; i < 4; i++)
#pragma unroll
      for (int j = 0; j < 4; j++) {
        int col = n0 + (wc << 6) + (j << 4) + l16;
        if (col >= ncmax) continue;
#pragma unroll
        for (int r = 0; r < 4; r++) {
          long row = m0 + (wr << 6) + (i << 4) + (quad << 2) + r;
          float v = acc[i][j][r];
          if (cf32) ((float*)C)[row * ldc + col] = v;
          else      ((bf16*)C)[row * ldc + col] = (bf16)v;
        }
      }
  }
}

// ---------------- GEMM wide (gemm1): 128M x 256N, BK=32, 512 thr / 8 waves ----------------
// R9 structure; A is now ALWAYS bf16 (pre-cast by cast_x), so the pure-DMA A path
// runs: gload16 issued at phase start (covered by compute) instead of the fp32
// wait->cvt->ds_write tail right before the barrier. fp32 branches retained but dead.
#define WBM 128
#define WBN 256
#define WBK 32

__global__ __launch_bounds__(512, 4) void gemm_bt_wide(
    const void* __restrict__ A, const bf16* __restrict__ Bt, bf16* __restrict__ C,
    int K, int ldc, int ncmax,
    bf16* __restrict__ vt_out, int vcol0, const int* __restrict__ flag) {
  alignas(16) __shared__ bf16 la[2 * WBM * WBK];  // 2 x 8 KB
  alignas(16) __shared__ bf16 lb[2 * WBN * WBK];  // 2 x 16 KB  (48 KB total)
  int fm = flag ? *flag : 1;
  bool af32 = !fm;  // flag=nullptr at call site -> always bf16 path
  int tid = threadIdx.x;
  int wave = tid >> 6, lane = tid & 63;
  int wm = wave >> 2, wn = wave & 3;  // 2M x 4N wave grid
  int quad = lane >> 4, l16 = lane & 15;

  // T1: XCD-aware block swizzle (384 % 8 == 0)
  int nwg = (int)(gridDim.x * gridDim.y);
  int flat = (int)(blockIdx.y * gridDim.x + blockIdx.x);
  int cpx = nwg >> 3;
  int wk = (flat & 7) * cpx + (flat >> 3);
  int bx = wk % (int)gridDim.x, by = wk / (int)gridDim.x;
  int m0 = by * WBM, n0 = bx * WBN;

  f32x4 acc[4][4] = {};

  // B staging: 2 gload16/wave; call u covers rows wave*32 + u*16 + (lane>>2)
  const bf16* gb[2];
  int lbo[2];
#pragma unroll
  for (int u = 0; u < 2; u++) {
    int sr2 = (wave << 5) + (u << 4) + (lane >> 2);
    int sc2 = (((lane & 3) - (sr2 >> 1)) & 3) << 3;  // rotated source chunk
    gb[u] = Bt + (long)(n0 + sr2) * K + sc2;
    lbo[u] = ((wave << 5) + (u << 4)) << 5;  // row_base * 32 elems (lane-linear dest)
  }
  // A staging (bf16): 1 gload16/wave, rows wave*16 + lane>>2, rotated source chunk
  const bf16* gaB = nullptr;
  const float* gaf = nullptr;
  int lao = (wave << 4) << 5;
  int fr = tid >> 2, fc = tid & 3;
  int wso = 0;
  if (af32) {
    gaf = (const float*)A + (long)(m0 + fr) * K + (fc << 3);
    wso = (fr << 5) + ((((fc) + (fr >> 1)) & 3) << 3);  // rotated write slot
  } else {
    int ra = (wave << 4) + (lane >> 2);
    int sca = (((lane & 3) - (ra >> 1)) & 3) << 3;
    gaB = (const bf16*)A + (long)(m0 + ra) * K + sca;
  }

  int nk = K / WBK;

  auto cvtwrite = [&](const float4* f, int buf) {
    alignas(16) bf16 tt[8];
    tt[0] = (bf16)f[0].x; tt[1] = (bf16)f[0].y; tt[2] = (bf16)f[0].z; tt[3] = (bf16)f[0].w;
    tt[4] = (bf16)f[1].x; tt[5] = (bf16)f[1].y; tt[6] = (bf16)f[1].z; tt[7] = (bf16)f[1].w;
    *(uint4*)(la + (buf << 12) + wso) = *(uint4*)tt;
  };
  auto compute = [&](int buf) {
    const bf16* baA = la + (buf << 12);
    const bf16* baB = lb + (buf << 13);
    bf16x8 afr[4], bfr[4];
#pragma unroll
    for (int i = 0; i < 4; i++) {
      int rowA = (wm << 6) + (i << 4) + l16;
      afr[i] = *(const bf16x8*)(baA + (rowA << 5) + (((quad + (rowA >> 1)) & 3) << 3));
    }
#pragma unroll
    for (int j = 0; j < 4; j++) {
      int rowB = (wn << 6) + (j << 4) + l16;
      bfr[j] = *(const bf16x8*)(baB + (rowB << 5) + (((quad + (rowB >> 1)) & 3) << 3));
    }
#pragma unroll
    for (int i = 0; i < 4; i++)
#pragma unroll
      for (int j = 0; j < 4; j++)
        acc[i][j] = __builtin_amdgcn_mfma_f32_16x16x32_bf16(afr[i], bfr[j], acc[i][j], 0, 0, 0);
  };

  // ---- prologue: stage tile 0 into buffer 0 ----
  gload16(gb[0], lb + lbo[0]);
  gload16(gb[1], lb + lbo[1]);
  if (af32) {
    float4 f0[2];
    f0[0] = *(const float4*)gaf;
    f0[1] = *(const float4*)(gaf + 4);
    cvtwrite(f0, 0);
  } else {
    gload16(gaB, la + lao);
  }
  __syncthreads();

  // ---- main loop: ONE barrier per K-step; stage t+1 overlaps compute t ----
  for (int t = 0; t < nk; ++t) {
    int cur = t & 1, nxt = cur ^ 1;
    bool hasnext = (t + 1 < nk);
    float4 f[2];
    if (hasnext) {
      int k0 = (t + 1) * WBK;
      gload16(gb[0] + k0, lb + (nxt << 13) + lbo[0]);
      gload16(gb[1] + k0, lb + (nxt << 13) + lbo[1]);
      if (af32) {
        f[0] = *(const float4*)(gaf + k0);
        f[1] = *(const float4*)(gaf + k0 + 4);
      } else {
        gload16(gaB + k0, la + (nxt << 12) + lao);
      }
    }

    compute(cur);

    if (hasnext && af32) cvtwrite(f, nxt);
    __syncthreads();
  }

  // epilogue: col = n0 + wn*64 + j*16 + l16; row = m0 + wm*64 + i*16 + quad*4 + r
  if (vt_out && n0 >= vcol0) {
#pragma unroll
    for (int i = 0; i < 4; i++)
#pragma unroll
      for (int j = 0; j < 4; j++) {
        int col = n0 + (wn << 6) + (j << 4) + l16;
        int hdg = col - vcol0;                            // 0..511 = kh*128+hd
        int row0 = m0 + (wm << 6) + (i << 4) + (quad << 2);
        int bb = row0 >> 11, s = row0 & 2047;
        ushort4 p;
        p.x = bfb(acc[i][j][0]); p.y = bfb(acc[i][j][1]);
        p.z = bfb(acc[i][j][2]); p.w = bfb(acc[i][j][3]);
        *(ushort4*)(vt_out + (((long)(bb * 512 + hdg)) << 11) + s) = p;
      }
  } else {
#pragma unroll
    for (int i = 0; i < 4; i++)
#pragma unroll
      for (int j = 0; j < 4; j++) {
        int col = n0 + (wn << 6) + (j << 4) + l16;
        if (col >= ncmax) continue;
#pragma unroll
        for (int r = 0; r < 4; r++) {
          long row = m0 + (wm << 6) + (i << 4) + (quad << 2) + r;
          C[row * ldc + col] = (bf16)acc[i][j][r];
        }
      }
  }
}

// ---------------- RoPE + scatter (Q pre-scaled by 1/sqrt(d)) ----------------
__global__ __launch_bounds__(256) void rope_scatter(
    const bf16* __restrict__ qkv, bf16* __restrict__ Q, bf16* __restrict__ Ko) {
  int row = blockIdx.x;  // b*S + s
  int b = row >> 11, s = row & 2047;
  int tid = threadIdx.x;
  int i = tid & 63;
  const bf16* src = qkv + (long)row * QKW;
  float theta = __expf(-0.14391156831212787f * (float)i);  // 10000^(-2i/128)
  float sn, cs;
  sincosf((float)s * theta, &sn, &cs);
#pragma unroll
  for (int it = 0; it < 4; ++it) {
    int h = (tid + it * 256) >> 6;  // 0..15 over the 4 iterations
    unsigned v = *(const unsigned*)(src + h * 128 + 2 * i);
    float x1 = __uint_as_float(v << 16);
    float x2 = __uint_as_float(v & 0xFFFF0000u);
    long qb = ((long)(b * H_ + h) * S_ + s) * HD_;
    Q[qb + i]      = (bf16)((x1 * cs - x2 * sn) * SCALE);
    Q[qb + 64 + i] = (bf16)((x1 * sn + x2 * cs) * SCALE);
  }
  {
    int kh = tid >> 6;
    unsigned v = *(const unsigned*)(src + 2048 + kh * 128 + 2 * i);
    float x1 = __uint_as_float(v << 16);
    float x2 = __uint_as_float(v & 0xFFFF0000u);
    long kb = ((long)(b * HKV_ + kh) * S_ + s) * HD_;
    Ko[kb + i]      = (bf16)(x1 * cs - x2 * sn);
    Ko[kb + 64 + i] = (bf16)(x1 * sn + x2 * cs);
  }
}

// ---------------- flash attention (R8 version, unchanged) ----------------
#define KTILE 8192  // 64 rows x 128 elems
#define VTILE 8192  // 128 rows x 64 elems

__global__ __launch_bounds__(256) void attn_kernel(
    const bf16* __restrict__ Q, const bf16* __restrict__ K,
    const bf16* __restrict__ Vt, bf16* __restrict__ O) {
  alignas(16) __shared__ bf16 Ks[2 * KTILE];  // 32 KB
  alignas(16) __shared__ bf16 Vs[2 * VTILE];  // 32 KB
  int bi = (int)blockIdx.x;        // 512 blocks, 1-D
  int cb = bi & 7;                 // XCD selector = (b, kh)
  int b = cb >> 2, kh = cb & 3;
  int r = bi >> 3;
  int qt0 = r >> 2;                // 0..15; paired with 31-qt0
  int h = kh * 4 + (r & 3);
  int tid = threadIdx.x, wave = tid >> 6, lane = tid & 63;
  int quad = lane >> 4, l16 = lane & 15;
  const bf16* Kg = K + ((long)(b * HKV_ + kh) * S_) * HD_;
  const bf16* Vg = Vt + ((long)(b * HKV_ + kh) * HD_) * S_;

  int kgo[4], vgo[4], klo[4], vlo[4];
#pragma unroll
  for (int u = 0; u < 4; u++) {
    int i = u * 4 + wave;
    int rr = i * 4 + quad;
    int c = l16 ^ (rr & 15);
    kgo[u] = rr * HD_ + c * 8;
    klo[u] = i * 512;
    int v = i * 8 + (lane >> 3);
    int cv = (lane & 7) ^ (v & 7);
    vgo[u] = v * S_ + cv * 8;
    vlo[u] = i * 512;
  }

  for (int hf = 0; hf < 2; ++hf) {
    int qt = hf ? 31 - qt0 : qt0;
    int q0 = qt * 64;
    const bf16* Qg = Q + ((long)(b * H_ + h) * S_ + q0) * HD_;

    bf16x8 qb[4];
    {
      const bf16* qrow = Qg + (wave * 16 + l16) * HD_ + quad * 8;
#pragma unroll
      for (int kk = 0; kk < 4; kk++) qb[kk] = *(const bf16x8*)(qrow + kk * 32);
    }

    if (hf) __syncthreads();

#pragma unroll
    for (int u = 0; u < 4; u++) {
      gload16(Kg + kgo[u], Ks + klo[u]);
      gload16(Vg + vgo[u], Vs + vlo[u]);
    }

    f32x4 Of[8] = {};
    float m_run = NEGINF, l_run = 0.f;

    for (int kt = 0; kt <= qt; ++kt) {
      __syncthreads();
      int p = kt & 1;
      if (kt < qt) {
        const bf16* kn = Kg + (long)(kt + 1) * 8192;
        const bf16* vn = Vg + (long)(kt + 1) * 64;
        bf16* kd = Ks + (p ^ 1) * KTILE;
        bf16* vd = Vs + (p ^ 1) * VTILE;
#pragma unroll
        for (int u = 0; u < 4; u++) {
          gload16(kn + kgo[u], kd + klo[u]);
          gload16(vn + vgo[u], vd + vlo[u]);
        }
      }
      const bf16* kc = Ks + p * KTILE;
      const bf16* vc = Vs + p * VTILE;

      bool diag = (kt == qt);
      f32x4 sf[4];
      __builtin_amdgcn_s_setprio(1);
#pragma unroll
      for (int jb = 0; jb < 4; jb++) {
        if (diag && jb > wave) {
          sf[jb] = (f32x4){NEGINF, NEGINF, NEGINF, NEGINF};
        } else {
          f32x4 a = {};
          const bf16* kbase = kc + (jb * 16 + l16) * 128;
#pragma unroll
          for (int kk = 0; kk < 4; kk++) {
            bf16x8 kf = *(const bf16x8*)(kbase + (((kk * 4 + quad) ^ l16) * 8));
            a = __builtin_amdgcn_mfma_f32_16x16x32_bf16(kf, qb[kk], a, 0, 0, 0);
          }
          sf[jb] = a;
        }
      }
      __builtin_amdgcn_s_setprio(0);
      if (diag) {
#pragma unroll
        for (int jb = 0; jb < 4; jb++)
          if (jb == wave) {
#pragma unroll
            for (int r2 = 0; r2 < 4; r2++)
              if (quad * 4 + r2 > l16) sf[jb][r2] = NEGINF;
          }
      }

      float mx = NEGINF;
#pragma unroll
      for (int jb = 0; jb < 4; jb++)
#pragma unroll
        for (int r2 = 0; r2 < 4; r2++) mx = fmaxf(mx, sf[jb][r2]);
      mx = fmaxf(mx, __shfl_xor(mx, 16));
      mx = fmaxf(mx, __shfl_xor(mx, 32));
      if (__any(mx > m_run + 8.0f)) {
        float mnew = fmaxf(m_run, mx);
        float alpha = __expf(m_run - mnew);
        m_run = mnew;
        l_run *= alpha;
#pragma unroll
        for (int n = 0; n < 8; n++) Of[n] *= alpha;
      }

      float ls = 0.f;
      s16x4 pk[4];
#pragma unroll
      for (int jb = 0; jb < 4; jb++) {
        float p0 = __expf(sf[jb][0] - m_run);
        float p1 = __expf(sf[jb][1] - m_run);
        float p2 = __expf(sf[jb][2] - m_run);
        float p3 = __expf(sf[jb][3] - m_run);
        ls += (p0 + p1) + (p2 + p3);
        s16x4 t;
        t.x = (short)bfb(p0); t.y = (short)bfb(p1);
        t.z = (short)bfb(p2); t.w = (short)bfb(p3);
        pk[jb] = t;
      }
      l_run += ls;

      __builtin_amdgcn_s_setprio(1);
#pragma unroll
      for (int jb = 0; jb < 4; jb++) {
        if (diag && jb > wave) continue;
#pragma unroll
        for (int n = 0; n < 8; n++) {
          int v = n * 16 + l16;
          const bf16* va_p = vc + v * 64 + (((jb * 2 + (quad >> 1)) ^ (l16 & 7)) * 8) + (quad & 1) * 4;
          s16x4 va = *(const s16x4*)va_p;
          Of[n] = __builtin_amdgcn_mfma_f32_16x16x16bf16_1k(va, pk[jb], Of[n], 0, 0, 0);
        }
      }
      __builtin_amdgcn_s_setprio(0);
    }

    l_run += __shfl_xor(l_run, 16);
    l_run += __shfl_xor(l_run, 32);
    float inv = 1.0f / fmaxf(l_run, 1e-30f);
    bf16* Ob = O + ((long)(b * S_) + q0 + wave * 16 + l16) * D_ + h * HD_;
#pragma unroll
    for (int n = 0; n < 8; n++) {
      ushort4 w;
      w.x = bfb(Of[n][0] * inv); w.y = bfb(Of[n][1] * inv);
      w.z = bfb(Of[n][2] * inv); w.w = bfb(Of[n][3] * inv);
      *(ushort4*)(Ob + n * 16 + quad * 4) = w;
    }
  }
}

// ---------------- launch ----------------
extern "C" void kernel_launch(void* const* d_in, const int* in_sizes, int n_in,
                              void* d_out, int out_size, void* d_ws, size_t ws_size,
                              hipStream_t stream) {
  const void* x  = d_in[0];
  const void* Wq = d_in[1];
  const void* Wk = d_in[2];
  const void* Wv = d_in[3];
  const void* Wo = d_in[4];
  bf16* ws = (bf16*)d_ws;
  int* flag = (int*)d_ws;

  // workspace (bf16 elem offsets), peak 23,068,688 elems = 46.1 MB (proven)
  bf16* qkv   = ws + 16;        // 4096 x 2560          gemm1 -> rope
  bf16* Vtb   = ws + 10485776;  // 2 x 512 x 2048       gemm1 epilogue -> attn
  bf16* Qb    = ws + 12582928;  // 2x16x2048x128        rope -> attn
  bf16* wqkvT = ws + 12582928;  // 3072x2048 (overlaps Qb; dead before rope writes)
  bf16* Kb    = ws + 20971536;  // 2x4x2048x128         rope -> attn
  bf16* attno = ws + 16;        // reuse qkv            attn -> gemm2
  bf16* woT   = ws + 10485776;  // reuse Vtb/Qb region  (transposed after attn)
  bf16* xb    = (bf16*)d_out;   // x in bf16 (d_out scratch; dead before gemm2 writes)

  dim3 tb(32, 8);
  detect_dtype<<<1, 256, 0, stream>>>((const unsigned*)x, flag);
  // x -> bf16 once (8.4M elems / 8 per thread / 256 per block = 4096 blocks)
  cast_x<<<4096, 256, 0, stream>>>(x, xb, flag);
  transpose_qkvw<<<dim3(64, 64, 3), tb, 0, stream>>>(Wq, Wk, Wv, wqkvT, flag);
  // qkv = xb @ [Wq|Wk|Wv]; q,k cols -> qkv (ldc 2560), v cols -> Vtb transposed.
  // flag=nullptr => pure-bf16 A path (gload_lds DMA, no in-loop cvt tail).
  gemm_bt_wide<<<dim3(QKVW / WBN, (B_ * S_) / WBM), 512, 0, stream>>>(
      xb, wqkvT, qkv, D_, QKW, QKW, Vtb, QKW, nullptr);
  rope_scatter<<<B_ * S_, 256, 0, stream>>>(qkv, Qb, Kb);
  // paired-causal 1-D grid: 512 blocks; low 3 bits = (b,kh) -> XCD partition
  attn_kernel<<<dim3(512, 1, 1), 256, 0, stream>>>(Qb, Kb, Vtb, attno);
  transpose_cvt<<<dim3(64, 64, 1), tb, 0, stream>>>(Wo, woT, 2048, 2048, flag);
  // out = attno @ Wo (output dtype per flag); overwrites xb scratch (dead by now)
  gemm_bt<<<dim3(D_ / BN, (B_ * S_) / BM), 256, 0, stream>>>(
      attno, woT, d_out, B_ * S_, D_, D_, D_, D_, nullptr, 0, flag, 0, 1);
}